// Round 2
// baseline (645.369 us; speedup 1.0000x reference)
//
#include <hip/hip_runtime.h>

#define BB 32
#define LL 8192
#define CC 64
#define TE 256
#define MM 33
#define KV 128
#define INVL (1.0f/8192.0f)
#define TWOPI 6.28318530717958647692f

// ws float offsets
#define TBL_OFF 0
#define TBL_SZ  (LL*64)            // 524288 floats (2 MB)
#define VX_OFF  (TBL_OFF + TBL_SZ) // per-batch V matrices [B][128][64]
#define VX_SZ   (BB*KV*CC)
#define D_OFF   (VX_OFF + VX_SZ)   // per-batch bias [B][64]
#define D_SZ    (BB*CC)
#define PS_OFF  (D_OFF + D_SZ)     // BN partials [2048][2][64]
#define NBLK_C  (BB*64)
#define PS_SZ   (NBLK_C*128)
#define MV_OFF  (PS_OFF + PS_SZ)   // mean[64], istd[64]

// scratch inside d_out (dead until k_main overwrites it)
#define SPART_OFF   0                 // [b][chunk64][i64][slot64]
#define SUMPART_OFF (BB*64*64*64)     // [b][chunk64][i64]

// ---------------------------------------------------------------------------
// Table: per l, 64 slots: slot0 = sin(m=32), slots 1..32 = cos(m=1..32),
// slots 33..63 = sin(m=1..31).  cos(m=0)=1 handled separately via plain sum.
__global__ __launch_bounds__(256) void k_tbl(float* __restrict__ ws) {
  int idx = blockIdx.x * 256 + threadIdx.x;   // < LL*64
  int l = idx >> 6, j = idx & 63;
  int m = (j == 0) ? 32 : (j <= 32 ? j : j - 32);
  bool is_sin = (j == 0) || (j >= 33);
  int r = (m * l) & (LL - 1);                 // exact phase reduction
  float ang = (float)r * (TWOPI / (float)LL);
  ws[TBL_OFF + idx] = is_sin ? sinf(ang) : cosf(ang);
}

// ---------------------------------------------------------------------------
// Phase A: truncated DFT.  lane = slot, x broadcast via uniform float4 loads.
// Each wave: one (b, chunk of 128 l, half of 64 channels).
__global__ __launch_bounds__(256) void k_dft(const float* __restrict__ x,
                                             const float* __restrict__ ws,
                                             float* __restrict__ scratch) {
  int w = threadIdx.x >> 6, lane = threadIdx.x & 63;
  int gw = blockIdx.x * 4 + w;       // 4096 waves
  int b = gw >> 7;                   // 128 waves per batch
  int ww = gw & 127;
  int chunk = ww >> 1, h = ww & 1;
  int l0 = chunk * 128, cbase = h * 32;

  float acc[32];
#pragma unroll
  for (int i = 0; i < 32; ++i) acc[i] = 0.f;
  float sum = 0.f;
  const float* tb = ws + TBL_OFF;

#pragma unroll 2
  for (int l = l0; l < l0 + 128; ++l) {
    int base = (b * LL + l) * CC;
    float tv = tb[l * 64 + lane];                       // per-lane table value
    const float4* xp = reinterpret_cast<const float4*>(x + base + cbase);
    float xl = x[base + cbase + (lane & 31)];
#pragma unroll
    for (int q = 0; q < 8; ++q) {
      float4 u = xp[q];                                 // uniform broadcast
      acc[4*q+0] = fmaf(tv, u.x, acc[4*q+0]);
      acc[4*q+1] = fmaf(tv, u.y, acc[4*q+1]);
      acc[4*q+2] = fmaf(tv, u.z, acc[4*q+2]);
      acc[4*q+3] = fmaf(tv, u.w, acc[4*q+3]);
    }
    sum += xl;
  }

  float* sp = scratch + SPART_OFF;
  int sbase = ((b * 64 + chunk) * 64 + cbase) * 64 + lane;
#pragma unroll
  for (int i = 0; i < 32; ++i) sp[sbase + i * 64] = acc[i];
  if (lane < 32)
    scratch[SUMPART_OFF + (b * 64 + chunk) * 64 + cbase + lane] = sum;
}

// ---------------------------------------------------------------------------
// Phase B: per-batch small algebra -> V[b] (128x64) and D[b] (64).
__global__ __launch_bounds__(256) void k_phaseB(
    const float* __restrict__ scratch, const float* __restrict__ t_emb,
    const float* __restrict__ swr, const float* __restrict__ swi,
    const float* __restrict__ dre, const float* __restrict__ dim_,
    const float* __restrict__ ck, const float* __restrict__ cbias,
    const float* __restrict__ tw, const float* __restrict__ pk,
    float* __restrict__ ws) {
  __shared__ float sS[64 * 64];
  __shared__ float sSum[64];
  __shared__ float sT[TE];
  __shared__ float sPsi[128];
  __shared__ float sTcr[MM], sTci[MM];
  __shared__ float sCr0[64];
  int tid = threadIdx.x, b = blockIdx.x;

  // reduce DFT partials over 64 chunks
  for (int p = tid; p < 4096; p += 256) {
    int i = p >> 6, j = p & 63;
    float a = 0.f;
#pragma unroll 4
    for (int ch = 0; ch < 64; ++ch)
      a += scratch[((b * 64 + ch) * 64 + i) * 64 + j];
    sS[p] = a;
  }
  if (tid < 64) {
    float a = 0.f;
#pragma unroll 4
    for (int ch = 0; ch < 64; ++ch)
      a += scratch[SUMPART_OFF + (b * 64 + ch) * 64 + tid];
    sSum[tid] = a;
  }
  sT[tid] = t_emb[b * TE + tid];
  __syncthreads();

  // psi = t_emb @ psi_kernel ; t_c = t_emb @ dense_{re,im}
  if (tid < 128) {
    float a = 0.f;
    for (int j = 0; j < TE; ++j) a = fmaf(sT[j], pk[j * 128 + tid], a);
    sPsi[tid] = a;
  } else if (tid < 128 + 66) {
    int tt = tid - 128;
    int m = (tt < 33) ? tt : tt - 33;
    const float* dd = (tt < 33) ? dre : dim_;
    float a = 0.f;
    for (int j = 0; j < TE; ++j) a = fmaf(sT[j], dd[j * MM + m], a);
    if (tt < 33) sTcr[m] = a; else sTci[m] = a;
  }
  __syncthreads();

  // spectral rows: R_m = t_c[m] * sum_i X[m,i] W[m,i,:]
  for (int q = tid; q < MM * 64; q += 256) {
    int m = q >> 6, o = q & 63;
    float ar = 0.f, ai = 0.f;
    for (int i = 0; i < 64; ++i) {
      float xr, xi;
      if (m == 0)       { xr = sSum[i] * INVL;        xi = 0.f; }
      else if (m < 32)  { xr = sS[i*64 + m] * INVL;   xi = -sS[i*64 + 32 + m] * INVL; }
      else              { xr = sS[i*64 + 32] * INVL;  xi = -sS[i*64 + 0] * INVL; }
      float wr = swr[(m * 64 + i) * 64 + o];
      float wi = swi[(m * 64 + i) * 64 + o];
      ar += xr * wr - xi * wi;
      ai += xr * wi + xi * wr;
    }
    float cr = sTcr[m] * ar - sTci[m] * ai;
    float ci = sTcr[m] * ai + sTci[m] * ar;
    float* vx = ws + VX_OFF + b * KV * 64;
    if (m == 0) {
      sCr0[o] = cr;                         // cos0 row folded into D
    } else {
      vx[(64 + m) * 64 + o] = 2.f * cr;     // cos slot m
      int js = (m == 32) ? 0 : 32 + m;      // sin slot
      vx[(64 + js) * 64 + o] = -2.f * ci;
    }
  }
  // M2 rows: M2[c,o] = sum_j ck[c,j] * psi[j] * tw[o,j]
  for (int q = tid; q < 4096; q += 256) {
    int c = q >> 6, o = q & 63;
    float a = 0.f;
    for (int j = 0; j < 64; ++j)
      a += ck[c * 64 + j] * sPsi[j] * tw[o * 64 + j];
    ws[VX_OFF + (b * KV + c) * 64 + o] = a;
  }
  __syncthreads();

  if (tid < 64) {
    int o = tid;
    float a = 0.f;
    for (int j = 0; j < 64; ++j)
      a += cbias[j] * sPsi[j] * tw[o * 64 + j];
    ws[D_OFF + b * 64 + o] = a + sPsi[64 + o] + sCr0[o];
  }
}

// ---------------------------------------------------------------------------
// Phase C: out_pre = U(128) @ V[b] + D[b], fused BN partial stats.
__global__ __launch_bounds__(256) void k_main(const float* __restrict__ x,
                                              float* __restrict__ ws,
                                              float* __restrict__ out) {
  __shared__ float sV[KV * 64];
  __shared__ float sD[64];
  __shared__ float sRed[256];
  int tid = threadIdx.x, w = tid >> 6, lane = tid & 63;
  int b = blockIdx.x >> 6, tile = blockIdx.x & 63;

  for (int r = tid; r < KV * 64; r += 256) sV[r] = ws[VX_OFF + b * KV * 64 + r];
  if (tid < 64) sD[tid] = ws[D_OFF + b * 64 + tid];
  __syncthreads();

  const float* tb = ws + TBL_OFF;
  int l0 = tile * 128 + w * 32;
  float s1 = 0.f, s2 = 0.f;

  for (int g = 0; g < 4; ++g) {
    int lb = l0 + g * 8;
    float acc[8];
#pragma unroll
    for (int e = 0; e < 8; ++e) acc[e] = 0.f;

#pragma unroll 2
    for (int k4 = 0; k4 < 16; ++k4) {          // x part (K 0..63)
      float v0 = sV[(4*k4+0) * 64 + lane];
      float v1 = sV[(4*k4+1) * 64 + lane];
      float v2 = sV[(4*k4+2) * 64 + lane];
      float v3 = sV[(4*k4+3) * 64 + lane];
#pragma unroll
      for (int e = 0; e < 8; ++e) {
        const float4 u = *reinterpret_cast<const float4*>(
            x + (b * LL + lb + e) * CC + 4 * k4);
        acc[e] = fmaf(u.x, v0, acc[e]);
        acc[e] = fmaf(u.y, v1, acc[e]);
        acc[e] = fmaf(u.z, v2, acc[e]);
        acc[e] = fmaf(u.w, v3, acc[e]);
      }
    }
#pragma unroll 2
    for (int j4 = 0; j4 < 16; ++j4) {          // table part (K 64..127)
      float v0 = sV[(64 + 4*j4 + 0) * 64 + lane];
      float v1 = sV[(64 + 4*j4 + 1) * 64 + lane];
      float v2 = sV[(64 + 4*j4 + 2) * 64 + lane];
      float v3 = sV[(64 + 4*j4 + 3) * 64 + lane];
#pragma unroll
      for (int e = 0; e < 8; ++e) {
        const float4 u = *reinterpret_cast<const float4*>(
            tb + (lb + e) * 64 + 4 * j4);
        acc[e] = fmaf(u.x, v0, acc[e]);
        acc[e] = fmaf(u.y, v1, acc[e]);
        acc[e] = fmaf(u.z, v2, acc[e]);
        acc[e] = fmaf(u.w, v3, acc[e]);
      }
    }
#pragma unroll
    for (int e = 0; e < 8; ++e) {
      float a = acc[e] + sD[lane];
      out[(b * LL + lb + e) * CC + lane] = a;
      s1 += a;
      s2 = fmaf(a, a, s2);
    }
  }

  sRed[w * 64 + lane] = s1;
  __syncthreads();
  if (w == 0) {
    float t = sRed[lane] + sRed[64+lane] + sRed[128+lane] + sRed[192+lane];
    ws[PS_OFF + blockIdx.x * 128 + lane] = t;
  }
  __syncthreads();
  sRed[w * 64 + lane] = s2;
  __syncthreads();
  if (w == 0) {
    float t = sRed[lane] + sRed[64+lane] + sRed[128+lane] + sRed[192+lane];
    ws[PS_OFF + blockIdx.x * 128 + 64 + lane] = t;
  }
}

// ---------------------------------------------------------------------------
__global__ __launch_bounds__(1024) void k_red(float* __restrict__ ws) {
  __shared__ float sr[1024];
  int t = threadIdx.x;
  int o = t & 63, s = (t >> 6) & 1, part = t >> 7;   // 8 parts
  float a = 0.f;
  for (int r = part * 256; r < part * 256 + 256; ++r)
    a += ws[PS_OFF + r * 128 + s * 64 + o];
  sr[t] = a;
  __syncthreads();
  if (t < 128) {
    float tot = 0.f;
#pragma unroll
    for (int p = 0; p < 8; ++p) tot += sr[p * 128 + t];
    sr[t] = tot;
  }
  __syncthreads();
  if (t < 64) {
    const float inv_n = 1.f / ((float)BB * (float)LL);
    float mean = sr[t] * inv_n;
    float ex2 = sr[64 + t] * inv_n;
    float var = ex2 - mean * mean;
    ws[MV_OFF + t] = mean;
    ws[MV_OFF + 64 + t] = rsqrtf(var + 1e-5f);
  }
}

// ---------------------------------------------------------------------------
__global__ __launch_bounds__(256) void k_apply(float* __restrict__ out,
                                               const float* __restrict__ ws,
                                               const float* __restrict__ bns,
                                               const float* __restrict__ bnb) {
  int gid = blockIdx.x * 256 + threadIdx.x;    // 524288 threads
  int c4 = gid & 15;
  const float4 mean = *reinterpret_cast<const float4*>(ws + MV_OFF + 4 * c4);
  const float4 istd = *reinterpret_cast<const float4*>(ws + MV_OFF + 64 + 4 * c4);
  const float4 sc   = *reinterpret_cast<const float4*>(bns + 4 * c4);
  const float4 bi   = *reinterpret_cast<const float4*>(bnb + 4 * c4);
  float4* po = reinterpret_cast<float4*>(out);
#pragma unroll
  for (int it = 0; it < 8; ++it) {
    int i4 = gid + it * 524288;
    float4 v = po[i4];
    v.x = fmaxf(fmaf((v.x - mean.x) * istd.x, sc.x, bi.x), 0.f);
    v.y = fmaxf(fmaf((v.y - mean.y) * istd.y, sc.y, bi.y), 0.f);
    v.z = fmaxf(fmaf((v.z - mean.z) * istd.z, sc.z, bi.z), 0.f);
    v.w = fmaxf(fmaf((v.w - mean.w) * istd.w, sc.w, bi.w), 0.f);
    po[i4] = v;
  }
}

// ---------------------------------------------------------------------------
extern "C" void kernel_launch(void* const* d_in, const int* in_sizes, int n_in,
                              void* d_out, int out_size, void* d_ws, size_t ws_size,
                              hipStream_t stream) {
  const float* x     = (const float*)d_in[0];
  const float* t_emb = (const float*)d_in[1];
  const float* swr   = (const float*)d_in[2];
  const float* swi   = (const float*)d_in[3];
  const float* dre   = (const float*)d_in[4];
  const float* dim_  = (const float*)d_in[5];
  const float* ck    = (const float*)d_in[6];
  const float* cbias = (const float*)d_in[7];
  const float* tw    = (const float*)d_in[8];
  const float* pk    = (const float*)d_in[9];
  const float* bns   = (const float*)d_in[10];
  const float* bnb   = (const float*)d_in[11];
  float* ws  = (float*)d_ws;
  float* out = (float*)d_out;

  k_tbl<<<2048, 256, 0, stream>>>(ws);
  k_dft<<<1024, 256, 0, stream>>>(x, ws, out);        // partials into d_out
  k_phaseB<<<32, 256, 0, stream>>>(out, t_emb, swr, swi, dre, dim_,
                                   ck, cbias, tw, pk, ws);
  k_main<<<2048, 256, 0, stream>>>(x, ws, out);       // overwrites d_out
  k_red<<<1, 1024, 0, stream>>>(ws);
  k_apply<<<2048, 256, 0, stream>>>(out, ws, bns, bnb);
}

// Round 3
// 278.293 us; speedup vs baseline: 2.3190x; 2.3190x over previous
//
#include <hip/hip_runtime.h>

typedef short short8 __attribute__((ext_vector_type(8)));
typedef float f32x4 __attribute__((ext_vector_type(4)));
typedef unsigned short u16;
typedef unsigned int u32;

#define BB 32
#define LL 8192
#define TE 256
#define MM 33
#define INVL (1.0f/8192.0f)
#define TWOPI 6.28318530717958647692f

// ws float offsets (all multiples of 4 -> 16B aligned)
#define TBLM_OFF 0               // Tb bf16 [8192][64]  (for k_main A, k=64..127)
#define TTD_OFF  262144          // Tt bf16 [80][8192]  (for k_dft A)
#define VTB_OFF  589824          // Vtb bf16 [32][64][128] (B operand, o-major)
#define DD_OFF   720896          // f32 [32][64] per-batch bias
#define PS_OFF   722944          // f32 [2048][128] BN partials
#define MV_OFF   985088          // mean[64], istd[64]

// d_out used as scratch for DFT partials: [32][16][80][64] f32 (10.5 MB of 64 MB)

static __device__ __forceinline__ u16 f2b(float f) {
  u32 u = __float_as_uint(f);
  return (u16)((u + 0x7FFFu + ((u >> 16) & 1u)) >> 16);   // RNE f32->bf16
}

// slot convention (j in 0..63): j=0: sin(m=32); j=1..32: cos(m=j); j=33..63: sin(m=j-32)
static __device__ __forceinline__ float slot_val(int j, int l) {
  int m = (j == 0) ? 32 : (j <= 32 ? j : j - 32);
  bool is_sin = (j == 0) || (j >= 33);
  int r = (m * l) & (LL - 1);
  float ang = (float)r * (TWOPI / (float)LL);
  return is_sin ? sinf(ang) : cosf(ang);
}

// ---------------------------------------------------------------------------
// Tb[l][j] bf16, coalesced in j.
__global__ __launch_bounds__(256) void k_tblA(float* __restrict__ ws) {
  int idx = blockIdx.x * 256 + threadIdx.x;   // < 8192*64
  int l = idx >> 6, j = idx & 63;
  ((u16*)ws)[TBLM_OFF * 2 + idx] = f2b(slot_val(j, l));
}

// Tt[j][l] bf16, coalesced in l.  j=64: ones row (m=0); j=65..79: zeros.
__global__ __launch_bounds__(256) void k_tblB(float* __restrict__ ws) {
  int j = blockIdx.x >> 5;                    // 0..79
  int l = (blockIdx.x & 31) * 256 + threadIdx.x;
  float v = (j < 64) ? slot_val(j, l) : (j == 64 ? 1.0f : 0.0f);
  ((u16*)ws)[TTD_OFF * 2 + j * LL + l] = f2b(v);
}

// ---------------------------------------------------------------------------
// Phase A: S[b][slot][ch] partials via MFMA.  512 blocks x 320 threads.
// Block (b, chunk of 512 l): 4 tiles of 128 l; wave w owns slot-tile w (16 slots).
__global__ __launch_bounds__(320) void k_dft(const float* __restrict__ x,
                                             const float* __restrict__ ws,
                                             float* __restrict__ scr) {
  __shared__ __align__(16) u16 sX[64 * 136];   // [ch][l'] transposed bf16
  int tid = threadIdx.x;
  int b = blockIdx.x >> 4, chunk = blockIdx.x & 15;
  int l0 = chunk * 512;
  int w = tid >> 6, lane = tid & 63;
  const u16* tt = (const u16*)ws + TTD_OFF * 2;

  f32x4 acc[4];
#pragma unroll
  for (int ct = 0; ct < 4; ++ct) acc[ct] = (f32x4){0.f, 0.f, 0.f, 0.f};

  int arow = lane & 15;
  int kb = (lane >> 4) * 8;

  for (int t = 0; t < 4; ++t) {
    int lt0 = l0 + t * 128;
    __syncthreads();
    for (int p = tid; p < 8192; p += 320) {
      int l = p >> 6, c = p & 63;
      sX[c * 136 + l] = f2b(x[(b * LL + lt0 + l) * 64 + c]);
    }
    __syncthreads();
#pragma unroll
    for (int kk = 0; kk < 4; ++kk) {
      short8 a = *reinterpret_cast<const short8*>(
          tt + (w * 16 + arow) * LL + lt0 + kk * 32 + kb);
#pragma unroll
      for (int ct = 0; ct < 4; ++ct) {
        short8 bf = *reinterpret_cast<const short8*>(&sX[(ct * 16 + arow) * 136 + kk * 32 + kb]);
        acc[ct] = __builtin_amdgcn_mfma_f32_16x16x32_bf16(a, bf, acc[ct], 0, 0, 0);
      }
    }
  }

  int rowb = (lane >> 4) * 4;
#pragma unroll
  for (int ct = 0; ct < 4; ++ct) {
    int ch = ct * 16 + (lane & 15);
#pragma unroll
    for (int r = 0; r < 4; ++r) {
      int sl = w * 16 + rowb + r;
      scr[((b * 16 + chunk) * 80 + sl) * 64 + ch] = acc[ct][r];
    }
  }
}

// ---------------------------------------------------------------------------
// Phase B: per-batch small algebra -> Vtb bf16 [b][o][128] and D[b][64].
__global__ __launch_bounds__(256) void k_phaseB(
    const float* __restrict__ scr, const float* __restrict__ t_emb,
    const float* __restrict__ swr, const float* __restrict__ swi,
    const float* __restrict__ dre, const float* __restrict__ dim_,
    const float* __restrict__ ck, const float* __restrict__ cbias,
    const float* __restrict__ tw, const float* __restrict__ pk,
    float* __restrict__ ws) {
  __shared__ float sS[65 * 64];    // [slot][ch]; slot 64 = plain sum
  __shared__ float sT[TE];
  __shared__ float sPsi[128];
  __shared__ float sTcr[MM], sTci[MM];
  __shared__ float sCr0[64];
  int tid = threadIdx.x, b = blockIdx.x;

  for (int p = tid; p < 65 * 64; p += 256) {
    int sl = p >> 6, i = p & 63;
    float a = 0.f;
#pragma unroll 4
    for (int cch = 0; cch < 16; ++cch)
      a += scr[((b * 16 + cch) * 80 + sl) * 64 + i];
    sS[p] = a;
  }
  sT[tid] = t_emb[b * TE + tid];
  __syncthreads();

  if (tid < 128) {
    float a = 0.f;
    for (int j = 0; j < TE; ++j) a = fmaf(sT[j], pk[j * 128 + tid], a);
    sPsi[tid] = a;
  } else if (tid < 128 + 66) {
    int tt = tid - 128;
    int m = (tt < 33) ? tt : tt - 33;
    const float* dd = (tt < 33) ? dre : dim_;
    float a = 0.f;
    for (int j = 0; j < TE; ++j) a = fmaf(sT[j], dd[j * MM + m], a);
    if (tt < 33) sTcr[m] = a; else sTci[m] = a;
  }
  __syncthreads();

  u16* vtb = (u16*)ws + VTB_OFF * 2 + b * 64 * 128;

  // spectral rows -> V k-rows 64..127
  for (int q = tid; q < MM * 64; q += 256) {
    int m = q >> 6, o = q & 63;
    float ar = 0.f, ai = 0.f;
    for (int i = 0; i < 64; ++i) {
      float xr, xi;
      if (m == 0)      { xr = sS[64 * 64 + i] * INVL; xi = 0.f; }
      else if (m < 32) { xr = sS[m * 64 + i] * INVL;  xi = -sS[(32 + m) * 64 + i] * INVL; }
      else             { xr = sS[32 * 64 + i] * INVL; xi = -sS[0 * 64 + i] * INVL; }
      float wr = swr[(m * 64 + i) * 64 + o];
      float wi = swi[(m * 64 + i) * 64 + o];
      ar += xr * wr - xi * wi;
      ai += xr * wi + xi * wr;
    }
    float cr = sTcr[m] * ar - sTci[m] * ai;
    float ci = sTcr[m] * ai + sTci[m] * ar;
    if (m == 0) {
      sCr0[o] = cr;                               // folded into D
    } else {
      vtb[o * 128 + 64 + m] = f2b(2.f * cr);      // cos slot m
      int js = (m == 32) ? 0 : 32 + m;            // sin slot
      vtb[o * 128 + 64 + js] = f2b(-2.f * ci);
    }
  }
  // M2 rows -> V k-rows 0..63: M2[c,o] = sum_j ck[c,j] psi[j] tw[o,j]
  for (int q = tid; q < 4096; q += 256) {
    int c = q >> 6, o = q & 63;
    float a = 0.f;
    for (int j = 0; j < 64; ++j)
      a += ck[c * 64 + j] * sPsi[j] * tw[o * 64 + j];
    vtb[o * 128 + c] = f2b(a);
  }
  __syncthreads();

  if (tid < 64) {
    int o = tid;
    float a = 0.f;
    for (int j = 0; j < 64; ++j)
      a += cbias[j] * sPsi[j] * tw[o * 64 + j];
    ws[DD_OFF + b * 64 + o] = a + sPsi[64 + o] + sCr0[o];
  }
}

// ---------------------------------------------------------------------------
// Phase C: out_pre = U(8192x128) @ V[b](128x64) + D[b] via MFMA, fused BN partials.
// 2048 blocks x 256; block = (b, 128 rows); wave owns 32 rows (2 row-tiles).
__global__ __launch_bounds__(256) void k_main(const float* __restrict__ x,
                                              float* __restrict__ ws,
                                              float* __restrict__ out) {
  __shared__ __align__(16) u16 sVt[64 * 136];   // [o][k] padded
  __shared__ float sD[64];
  __shared__ float sRed[4 * 128];
  int tid = threadIdx.x, w = tid >> 6, lane = tid & 63;
  int b = blockIdx.x >> 6, rg = blockIdx.x & 63;
  const u16* wsu = (const u16*)ws;

  {
    const u32* src = (const u32*)(wsu + VTB_OFF * 2 + b * 64 * 128);
    u32* dst = (u32*)sVt;
    for (int p = tid; p < 4096; p += 256)
      dst[(p >> 6) * 68 + (p & 63)] = src[p];
  }
  if (tid < 64) sD[tid] = ws[DD_OFF + b * 64 + tid];
  __syncthreads();

  int kb = (lane >> 4) * 8;
  short8 bf[4][4];
#pragma unroll
  for (int kk = 0; kk < 4; ++kk)
#pragma unroll
    for (int ct = 0; ct < 4; ++ct)
      bf[kk][ct] = *reinterpret_cast<const short8*>(
          &sVt[(ct * 16 + (lane & 15)) * 136 + kk * 32 + kb]);

  const u16* tb = wsu + TBLM_OFF * 2;
  float s1[4] = {0.f, 0.f, 0.f, 0.f}, s2[4] = {0.f, 0.f, 0.f, 0.f};
  int rowb = (lane >> 4) * 4;
  int lbase = rg * 128 + w * 32;

#pragma unroll
  for (int rt = 0; rt < 2; ++rt) {
    int l = lbase + rt * 16 + (lane & 15);
    const float* xq = x + (b * LL + l) * 64;
    float4 u0 = *reinterpret_cast<const float4*>(xq + kb);
    float4 u1 = *reinterpret_cast<const float4*>(xq + kb + 4);
    float4 u2 = *reinterpret_cast<const float4*>(xq + 32 + kb);
    float4 u3 = *reinterpret_cast<const float4*>(xq + 32 + kb + 4);
    short8 a0, a1;
    a0[0] = (short)f2b(u0.x); a0[1] = (short)f2b(u0.y);
    a0[2] = (short)f2b(u0.z); a0[3] = (short)f2b(u0.w);
    a0[4] = (short)f2b(u1.x); a0[5] = (short)f2b(u1.y);
    a0[6] = (short)f2b(u1.z); a0[7] = (short)f2b(u1.w);
    a1[0] = (short)f2b(u2.x); a1[1] = (short)f2b(u2.y);
    a1[2] = (short)f2b(u2.z); a1[3] = (short)f2b(u2.w);
    a1[4] = (short)f2b(u3.x); a1[5] = (short)f2b(u3.y);
    a1[6] = (short)f2b(u3.z); a1[7] = (short)f2b(u3.w);
    short8 a2 = *reinterpret_cast<const short8*>(tb + l * 64 + kb);
    short8 a3 = *reinterpret_cast<const short8*>(tb + l * 64 + 32 + kb);

    f32x4 acc[4];
#pragma unroll
    for (int ct = 0; ct < 4; ++ct) acc[ct] = (f32x4){0.f, 0.f, 0.f, 0.f};
#pragma unroll
    for (int ct = 0; ct < 4; ++ct) {
      acc[ct] = __builtin_amdgcn_mfma_f32_16x16x32_bf16(a0, bf[0][ct], acc[ct], 0, 0, 0);
      acc[ct] = __builtin_amdgcn_mfma_f32_16x16x32_bf16(a1, bf[1][ct], acc[ct], 0, 0, 0);
      acc[ct] = __builtin_amdgcn_mfma_f32_16x16x32_bf16(a2, bf[2][ct], acc[ct], 0, 0, 0);
      acc[ct] = __builtin_amdgcn_mfma_f32_16x16x32_bf16(a3, bf[3][ct], acc[ct], 0, 0, 0);
    }
#pragma unroll
    for (int ct = 0; ct < 4; ++ct) {
      int o = ct * 16 + (lane & 15);
      float dd = sD[o];
#pragma unroll
      for (int r = 0; r < 4; ++r) {
        float v = acc[ct][r] + dd;
        out[(b * LL + lbase + rt * 16 + rowb + r) * 64 + o] = v;
        s1[ct] += v;
        s2[ct] = fmaf(v, v, s2[ct]);
      }
    }
  }

#pragma unroll
  for (int ct = 0; ct < 4; ++ct) {
    s1[ct] += __shfl_xor(s1[ct], 16); s1[ct] += __shfl_xor(s1[ct], 32);
    s2[ct] += __shfl_xor(s2[ct], 16); s2[ct] += __shfl_xor(s2[ct], 32);
  }
  if (lane < 16) {
#pragma unroll
    for (int ct = 0; ct < 4; ++ct) {
      sRed[w * 128 + ct * 16 + lane] = s1[ct];
      sRed[w * 128 + 64 + ct * 16 + lane] = s2[ct];
    }
  }
  __syncthreads();
  if (tid < 128) {
    float t = sRed[tid] + sRed[128 + tid] + sRed[256 + tid] + sRed[384 + tid];
    ws[PS_OFF + blockIdx.x * 128 + tid] = t;
  }
}

// ---------------------------------------------------------------------------
__global__ __launch_bounds__(1024) void k_red(float* __restrict__ ws) {
  __shared__ float sr[1024];
  int t = threadIdx.x;
  int o = t & 63, s = (t >> 6) & 1, part = t >> 7;
  float a = 0.f;
  for (int r = part * 256; r < part * 256 + 256; ++r)
    a += ws[PS_OFF + r * 128 + s * 64 + o];
  sr[t] = a;
  __syncthreads();
  if (t < 128) {
    float tot = 0.f;
#pragma unroll
    for (int p = 0; p < 8; ++p) tot += sr[p * 128 + t];
    sr[t] = tot;
  }
  __syncthreads();
  if (t < 64) {
    const float inv_n = 1.f / ((float)BB * (float)LL);
    float mean = sr[t] * inv_n;
    float ex2 = sr[64 + t] * inv_n;
    float var = ex2 - mean * mean;
    ws[MV_OFF + t] = mean;
    ws[MV_OFF + 64 + t] = rsqrtf(var + 1e-5f);
  }
}

// ---------------------------------------------------------------------------
__global__ __launch_bounds__(256) void k_apply(float* __restrict__ out,
                                               const float* __restrict__ ws,
                                               const float* __restrict__ bns,
                                               const float* __restrict__ bnb) {
  int gid = blockIdx.x * 256 + threadIdx.x;
  int c4 = gid & 15;
  const float4 mean = *reinterpret_cast<const float4*>(ws + MV_OFF + 4 * c4);
  const float4 istd = *reinterpret_cast<const float4*>(ws + MV_OFF + 64 + 4 * c4);
  const float4 sc   = *reinterpret_cast<const float4*>(bns + 4 * c4);
  const float4 bi   = *reinterpret_cast<const float4*>(bnb + 4 * c4);
  float4* po = reinterpret_cast<float4*>(out);
#pragma unroll
  for (int it = 0; it < 8; ++it) {
    int i4 = gid + it * 524288;
    float4 v = po[i4];
    v.x = fmaxf(fmaf((v.x - mean.x) * istd.x, sc.x, bi.x), 0.f);
    v.y = fmaxf(fmaf((v.y - mean.y) * istd.y, sc.y, bi.y), 0.f);
    v.z = fmaxf(fmaf((v.z - mean.z) * istd.z, sc.z, bi.z), 0.f);
    v.w = fmaxf(fmaf((v.w - mean.w) * istd.w, sc.w, bi.w), 0.f);
    po[i4] = v;
  }
}

// ---------------------------------------------------------------------------
extern "C" void kernel_launch(void* const* d_in, const int* in_sizes, int n_in,
                              void* d_out, int out_size, void* d_ws, size_t ws_size,
                              hipStream_t stream) {
  const float* x     = (const float*)d_in[0];
  const float* t_emb = (const float*)d_in[1];
  const float* swr   = (const float*)d_in[2];
  const float* swi   = (const float*)d_in[3];
  const float* dre   = (const float*)d_in[4];
  const float* dim_  = (const float*)d_in[5];
  const float* ck    = (const float*)d_in[6];
  const float* cbias = (const float*)d_in[7];
  const float* tw    = (const float*)d_in[8];
  const float* pk    = (const float*)d_in[9];
  const float* bns   = (const float*)d_in[10];
  const float* bnb   = (const float*)d_in[11];
  float* ws  = (float*)d_ws;
  float* out = (float*)d_out;

  k_tblA<<<2048, 256, 0, stream>>>(ws);
  k_tblB<<<2560, 256, 0, stream>>>(ws);
  k_dft<<<512, 320, 0, stream>>>(x, ws, out);         // partials into d_out
  k_phaseB<<<32, 256, 0, stream>>>(out, t_emb, swr, swi, dre, dim_,
                                   ck, cbias, tw, pk, ws);
  k_main<<<2048, 256, 0, stream>>>(x, ws, out);       // overwrites d_out
  k_red<<<1, 1024, 0, stream>>>(ws);
  k_apply<<<2048, 256, 0, stream>>>(out, ws, bns, bnb);
}

// Round 4
// 187.435 us; speedup vs baseline: 3.4432x; 1.4847x over previous
//
#include <hip/hip_runtime.h>

typedef short short8 __attribute__((ext_vector_type(8)));
typedef float f32x4 __attribute__((ext_vector_type(4)));
typedef unsigned short u16;
typedef unsigned int u32;

#define BB 32
#define LL 8192
#define TE 256
#define MM 33
#define INVL (1.0f/8192.0f)
#define TWOPI 6.28318530717958647692f

// ws float offsets
#define TBLM_OFF 0               // Tb bf16 [8192][64]
#define TTD_OFF  262144          // Tt bf16 [80][8192]
#define VTB_OFF  589824          // Vtb bf16 [32][64][128]
#define DD_OFF   720896          // f32 [32][64]  (M2-branch bias)
#define DD2_OFF  722944          // f32 [32][64]  (cos0 spectral bias)
#define PSI_OFF  724992          // f32 [32][128]
#define TC_OFF   729088          // f32 [32][66]  (tcr[33], tci[33])
#define PS_OFF   731200          // f32 [2048][128] BN partials; SRED aliases this
#define SRED_OFF PS_OFF          // f32 [32][65][64] (dead before k_main)
#define MV_OFF   993344          // mean[64], istd[64]

// d_out used as scratch for DFT partials: [32][16][80][64] f32

static __device__ __forceinline__ u16 f2b(float f) {
  u32 u = __float_as_uint(f);
  return (u16)((u + 0x7FFFu + ((u >> 16) & 1u)) >> 16);   // RNE f32->bf16
}

// slot convention (j in 0..63): j=0: sin(m=32); j=1..32: cos(m=j); j=33..63: sin(m=j-32)
static __device__ __forceinline__ float slot_val(int j, int l) {
  int m = (j == 0) ? 32 : (j <= 32 ? j : j - 32);
  bool is_sin = (j == 0) || (j >= 33);
  int r = (m * l) & (LL - 1);
  float ang = (float)r * (TWOPI / (float)LL);
  return is_sin ? sinf(ang) : cosf(ang);
}

// ---------------------------------------------------------------------------
__global__ __launch_bounds__(256) void k_tblA(float* __restrict__ ws) {
  int idx = blockIdx.x * 256 + threadIdx.x;   // < 8192*64
  int l = idx >> 6, j = idx & 63;
  ((u16*)ws)[TBLM_OFF * 2 + idx] = f2b(slot_val(j, l));
}

__global__ __launch_bounds__(256) void k_tblB(float* __restrict__ ws) {
  int j = blockIdx.x >> 5;                    // 0..79
  int l = (blockIdx.x & 31) * 256 + threadIdx.x;
  float v = (j < 64) ? slot_val(j, l) : (j == 64 ? 1.0f : 0.0f);
  ((u16*)ws)[TTD_OFF * 2 + j * LL + l] = f2b(v);
}

// ---------------------------------------------------------------------------
// Phase A: S[b][slot][ch] partials via MFMA.  512 blocks x 320 threads.
__global__ __launch_bounds__(320) void k_dft(const float* __restrict__ x,
                                             const float* __restrict__ ws,
                                             float* __restrict__ scr) {
  __shared__ __align__(16) u16 sX[64 * 136];   // [ch][l'] transposed bf16
  int tid = threadIdx.x;
  int b = blockIdx.x >> 4, chunk = blockIdx.x & 15;
  int l0 = chunk * 512;
  int w = tid >> 6, lane = tid & 63;
  const u16* tt = (const u16*)ws + TTD_OFF * 2;

  f32x4 acc[4];
#pragma unroll
  for (int ct = 0; ct < 4; ++ct) acc[ct] = (f32x4){0.f, 0.f, 0.f, 0.f};

  int arow = lane & 15;
  int kb = (lane >> 4) * 8;

  for (int t = 0; t < 4; ++t) {
    int lt0 = l0 + t * 128;
    __syncthreads();
    for (int p = tid; p < 8192; p += 320) {
      int l = p >> 6, c = p & 63;
      sX[c * 136 + l] = f2b(x[(b * LL + lt0 + l) * 64 + c]);
    }
    __syncthreads();
#pragma unroll
    for (int kk = 0; kk < 4; ++kk) {
      short8 a = *reinterpret_cast<const short8*>(
          tt + (w * 16 + arow) * LL + lt0 + kk * 32 + kb);
#pragma unroll
      for (int ct = 0; ct < 4; ++ct) {
        short8 bf = *reinterpret_cast<const short8*>(&sX[(ct * 16 + arow) * 136 + kk * 32 + kb]);
        acc[ct] = __builtin_amdgcn_mfma_f32_16x16x32_bf16(a, bf, acc[ct], 0, 0, 0);
      }
    }
  }

  int rowb = (lane >> 4) * 4;
#pragma unroll
  for (int ct = 0; ct < 4; ++ct) {
    int ch = ct * 16 + (lane & 15);
#pragma unroll
    for (int r = 0; r < 4; ++r) {
      int sl = w * 16 + rowb + r;
      scr[((b * 16 + chunk) * 80 + sl) * 64 + ch] = acc[ct][r];
    }
  }
}

// ---------------------------------------------------------------------------
// Reduce DFT partials over 16 chunks -> SRED[b][65][64].
__global__ __launch_bounds__(256) void k_red1(const float* __restrict__ scr,
                                              float* __restrict__ ws) {
  int b = blockIdx.y;
  int r = blockIdx.x * 256 + threadIdx.x;     // sl*64+i
  if (r >= 65 * 64) return;
  float a = 0.f;
#pragma unroll
  for (int ch = 0; ch < 16; ++ch) a += scr[(b * 16 + ch) * 5120 + r];
  ws[SRED_OFF + b * 4160 + r] = a;
}

// ---------------------------------------------------------------------------
// psi = t_emb @ psi_kernel ; t_c = t_emb @ dense_{re,im}.  32 blocks.
__global__ __launch_bounds__(256) void k_small(const float* __restrict__ t_emb,
                                               const float* __restrict__ dre,
                                               const float* __restrict__ dim_,
                                               const float* __restrict__ pk,
                                               float* __restrict__ ws) {
  __shared__ float sT[TE];
  int tid = threadIdx.x, b = blockIdx.x;
  sT[tid] = t_emb[b * TE + tid];
  __syncthreads();
  if (tid < 128) {
    float a = 0.f;
#pragma unroll 8
    for (int j = 0; j < TE; ++j) a = fmaf(sT[j], pk[j * 128 + tid], a);
    ws[PSI_OFF + b * 128 + tid] = a;
  } else if (tid < 128 + 66) {
    int tt = tid - 128;
    int m = (tt < 33) ? tt : tt - 33;
    const float* dd = (tt < 33) ? dre : dim_;
    float a = 0.f;
#pragma unroll 8
    for (int j = 0; j < TE; ++j) a = fmaf(sT[j], dd[j * MM + m], a);
    ws[TC_OFF + b * 66 + tt] = a;
  }
}

// ---------------------------------------------------------------------------
// Spectral contraction, one block per mode m (33 blocks x 256).
// R[b,m,o] = t_c[b,m] * sum_i X[b,m,i] W[m,i,o] -> V rows 64..127 (bf16).
__global__ __launch_bounds__(256) void k_spec(const float* __restrict__ swr,
                                              const float* __restrict__ swi,
                                              float* __restrict__ ws) {
  __shared__ float2 sW[64 * 64];   // [i][o] (re,im)
  __shared__ float2 sX[32 * 64];   // [b][i] (re,im)
  __shared__ float sTcb[64];       // tcr[32], tci[32]
  int tid = threadIdx.x, m = blockIdx.x;

  for (int idx = tid; idx < 4096; idx += 256) {
    float wr = swr[m * 4096 + idx];
    float wi = swi[m * 4096 + idx];
    sW[idx] = make_float2(wr, wi);
  }
  for (int idx = tid; idx < 2048; idx += 256) {
    int b = idx >> 6, i = idx & 63;
    const float* sr = ws + SRED_OFF + b * 4160;
    float xr, xi;
    if (m == 0)      { xr = sr[64 * 64 + i] * INVL;      xi = 0.f; }
    else if (m < 32) { xr = sr[m * 64 + i] * INVL;       xi = -sr[(32 + m) * 64 + i] * INVL; }
    else             { xr = sr[32 * 64 + i] * INVL;      xi = -sr[0 * 64 + i] * INVL; }
    sX[idx] = make_float2(xr, xi);
  }
  if (tid < 64) {
    int b = tid & 31, half = tid >> 5;
    sTcb[tid] = ws[TC_OFF + b * 66 + half * 33 + m];
  }
  __syncthreads();

  int w = tid >> 6, lane = tid & 63;
  for (int p = 0; p < 8; ++p) {
    int b = p * 4 + w;
    float a0 = 0.f, a1 = 0.f, a2 = 0.f, a3 = 0.f;
#pragma unroll 16
    for (int i = 0; i < 64; ++i) {
      float2 wv = sW[i * 64 + lane];
      float2 xv = sX[b * 64 + i];
      a0 = fmaf(xv.x, wv.x, a0);
      a1 = fmaf(xv.y, wv.y, a1);
      a2 = fmaf(xv.x, wv.y, a2);
      a3 = fmaf(xv.y, wv.x, a3);
    }
    float ar = a0 - a1, ai = a2 + a3;
    float tcr = sTcb[b], tci = sTcb[32 + b];
    float cr = tcr * ar - tci * ai;
    float ci = tcr * ai + tci * ar;
    if (m == 0) {
      ws[DD2_OFF + b * 64 + lane] = cr;
    } else {
      u16* vtb = (u16*)ws + VTB_OFF * 2 + (b * 64 + lane) * 128;
      vtb[64 + m] = f2b(2.f * cr);
      vtb[64 + ((m == 32) ? 0 : 32 + m)] = f2b(-2.f * ci);
    }
  }
}

// ---------------------------------------------------------------------------
// M2[b][c][o] = sum_j ck[c,j] psi[b,j] tw[o,j] -> V rows 0..63; D1[b][o].
__global__ __launch_bounds__(256) void k_m2(const float* __restrict__ ck,
                                            const float* __restrict__ cbias,
                                            const float* __restrict__ tw,
                                            float* __restrict__ ws) {
  __shared__ float sCkT[64 * 64];   // [j][c]
  __shared__ float sPtw[64 * 64];   // [o][j] = psi[j]*tw[o][j]
  __shared__ float sPsi[128];
  int tid = threadIdx.x, b = blockIdx.x;

  if (tid < 128) sPsi[tid] = ws[PSI_OFF + b * 128 + tid];
  __syncthreads();
  for (int idx = tid; idx < 4096; idx += 256) {
    int c = idx >> 6, j = idx & 63;
    sCkT[j * 64 + c] = ck[idx];
    sPtw[idx] = sPsi[j] * tw[idx];     // idx = o*64+j
  }
  __syncthreads();

  u16* vtb = (u16*)ws + VTB_OFF * 2 + b * 64 * 128;
  int lane = tid & 63, w = tid >> 6;
#pragma unroll 4
  for (int it = 0; it < 16; ++it) {
    int o = it * 4 + w;              // wave-uniform
    float a = 0.f;
#pragma unroll 16
    for (int j = 0; j < 64; ++j)
      a = fmaf(sCkT[j * 64 + lane], sPtw[o * 64 + j], a);
    vtb[o * 128 + lane] = f2b(a);
  }
  if (tid < 64) {
    float a = 0.f;
    for (int j = 0; j < 64; ++j) a = fmaf(cbias[j], sPtw[tid * 64 + j], a);
    ws[DD_OFF + b * 64 + tid] = a + sPsi[64 + tid];
  }
}

// ---------------------------------------------------------------------------
// Phase C: out_pre = U(8192x128) @ V[b](128x64) + D[b] via MFMA, fused BN stats.
__global__ __launch_bounds__(256) void k_main(const float* __restrict__ x,
                                              float* __restrict__ ws,
                                              float* __restrict__ out) {
  __shared__ __align__(16) u16 sVt[64 * 136];
  __shared__ float sD[64];
  __shared__ float sRed[4 * 128];
  int tid = threadIdx.x, w = tid >> 6, lane = tid & 63;
  int b = blockIdx.x >> 6, rg = blockIdx.x & 63;
  const u16* wsu = (const u16*)ws;

  {
    const u32* src = (const u32*)(wsu + VTB_OFF * 2 + b * 64 * 128);
    u32* dst = (u32*)sVt;
    for (int p = tid; p < 4096; p += 256)
      dst[(p >> 6) * 68 + (p & 63)] = src[p];
  }
  if (tid < 64) sD[tid] = ws[DD_OFF + b * 64 + tid] + ws[DD2_OFF + b * 64 + tid];
  __syncthreads();

  int kb = (lane >> 4) * 8;
  short8 bf[4][4];
#pragma unroll
  for (int kk = 0; kk < 4; ++kk)
#pragma unroll
    for (int ct = 0; ct < 4; ++ct)
      bf[kk][ct] = *reinterpret_cast<const short8*>(
          &sVt[(ct * 16 + (lane & 15)) * 136 + kk * 32 + kb]);

  const u16* tb = wsu + TBLM_OFF * 2;
  float s1[4] = {0.f, 0.f, 0.f, 0.f}, s2[4] = {0.f, 0.f, 0.f, 0.f};
  int rowb = (lane >> 4) * 4;
  int lbase = rg * 128 + w * 32;

#pragma unroll
  for (int rt = 0; rt < 2; ++rt) {
    int l = lbase + rt * 16 + (lane & 15);
    const float* xq = x + (b * LL + l) * 64;
    float4 u0 = *reinterpret_cast<const float4*>(xq + kb);
    float4 u1 = *reinterpret_cast<const float4*>(xq + kb + 4);
    float4 u2 = *reinterpret_cast<const float4*>(xq + 32 + kb);
    float4 u3 = *reinterpret_cast<const float4*>(xq + 32 + kb + 4);
    short8 a0, a1;
    a0[0] = (short)f2b(u0.x); a0[1] = (short)f2b(u0.y);
    a0[2] = (short)f2b(u0.z); a0[3] = (short)f2b(u0.w);
    a0[4] = (short)f2b(u1.x); a0[5] = (short)f2b(u1.y);
    a0[6] = (short)f2b(u1.z); a0[7] = (short)f2b(u1.w);
    a1[0] = (short)f2b(u2.x); a1[1] = (short)f2b(u2.y);
    a1[2] = (short)f2b(u2.z); a1[3] = (short)f2b(u2.w);
    a1[4] = (short)f2b(u3.x); a1[5] = (short)f2b(u3.y);
    a1[6] = (short)f2b(u3.z); a1[7] = (short)f2b(u3.w);
    short8 a2 = *reinterpret_cast<const short8*>(tb + l * 64 + kb);
    short8 a3 = *reinterpret_cast<const short8*>(tb + l * 64 + 32 + kb);

    f32x4 acc[4];
#pragma unroll
    for (int ct = 0; ct < 4; ++ct) acc[ct] = (f32x4){0.f, 0.f, 0.f, 0.f};
#pragma unroll
    for (int ct = 0; ct < 4; ++ct) {
      acc[ct] = __builtin_amdgcn_mfma_f32_16x16x32_bf16(a0, bf[0][ct], acc[ct], 0, 0, 0);
      acc[ct] = __builtin_amdgcn_mfma_f32_16x16x32_bf16(a1, bf[1][ct], acc[ct], 0, 0, 0);
      acc[ct] = __builtin_amdgcn_mfma_f32_16x16x32_bf16(a2, bf[2][ct], acc[ct], 0, 0, 0);
      acc[ct] = __builtin_amdgcn_mfma_f32_16x16x32_bf16(a3, bf[3][ct], acc[ct], 0, 0, 0);
    }
#pragma unroll
    for (int ct = 0; ct < 4; ++ct) {
      int o = ct * 16 + (lane & 15);
      float dd = sD[o];
#pragma unroll
      for (int r = 0; r < 4; ++r) {
        float v = acc[ct][r] + dd;
        out[(b * LL + lbase + rt * 16 + rowb + r) * 64 + o] = v;
        s1[ct] += v;
        s2[ct] = fmaf(v, v, s2[ct]);
      }
    }
  }

#pragma unroll
  for (int ct = 0; ct < 4; ++ct) {
    s1[ct] += __shfl_xor(s1[ct], 16); s1[ct] += __shfl_xor(s1[ct], 32);
    s2[ct] += __shfl_xor(s2[ct], 16); s2[ct] += __shfl_xor(s2[ct], 32);
  }
  if (lane < 16) {
#pragma unroll
    for (int ct = 0; ct < 4; ++ct) {
      sRed[w * 128 + ct * 16 + lane] = s1[ct];
      sRed[w * 128 + 64 + ct * 16 + lane] = s2[ct];
    }
  }
  __syncthreads();
  if (tid < 128) {
    float t = sRed[tid] + sRed[128 + tid] + sRed[256 + tid] + sRed[384 + tid];
    ws[PS_OFF + blockIdx.x * 128 + tid] = t;
  }
}

// ---------------------------------------------------------------------------
__global__ __launch_bounds__(1024) void k_red(float* __restrict__ ws) {
  __shared__ float sr[1024];
  int t = threadIdx.x;
  int o = t & 63, s = (t >> 6) & 1, part = t >> 7;
  float a = 0.f;
  for (int r = part * 256; r < part * 256 + 256; ++r)
    a += ws[PS_OFF + r * 128 + s * 64 + o];
  sr[t] = a;
  __syncthreads();
  if (t < 128) {
    float tot = 0.f;
#pragma unroll
    for (int p = 0; p < 8; ++p) tot += sr[p * 128 + t];
    sr[t] = tot;
  }
  __syncthreads();
  if (t < 64) {
    const float inv_n = 1.f / ((float)BB * (float)LL);
    float mean = sr[t] * inv_n;
    float ex2 = sr[64 + t] * inv_n;
    float var = ex2 - mean * mean;
    ws[MV_OFF + t] = mean;
    ws[MV_OFF + 64 + t] = rsqrtf(var + 1e-5f);
  }
}

// ---------------------------------------------------------------------------
__global__ __launch_bounds__(256) void k_apply(float* __restrict__ out,
                                               const float* __restrict__ ws,
                                               const float* __restrict__ bns,
                                               const float* __restrict__ bnb) {
  int gid = blockIdx.x * 256 + threadIdx.x;
  int c4 = gid & 15;
  const float4 mean = *reinterpret_cast<const float4*>(ws + MV_OFF + 4 * c4);
  const float4 istd = *reinterpret_cast<const float4*>(ws + MV_OFF + 64 + 4 * c4);
  const float4 sc   = *reinterpret_cast<const float4*>(bns + 4 * c4);
  const float4 bi   = *reinterpret_cast<const float4*>(bnb + 4 * c4);
  float4* po = reinterpret_cast<float4*>(out);
#pragma unroll
  for (int it = 0; it < 8; ++it) {
    int i4 = gid + it * 524288;
    float4 v = po[i4];
    v.x = fmaxf(fmaf((v.x - mean.x) * istd.x, sc.x, bi.x), 0.f);
    v.y = fmaxf(fmaf((v.y - mean.y) * istd.y, sc.y, bi.y), 0.f);
    v.z = fmaxf(fmaf((v.z - mean.z) * istd.z, sc.z, bi.z), 0.f);
    v.w = fmaxf(fmaf((v.w - mean.w) * istd.w, sc.w, bi.w), 0.f);
    po[i4] = v;
  }
}

// ---------------------------------------------------------------------------
extern "C" void kernel_launch(void* const* d_in, const int* in_sizes, int n_in,
                              void* d_out, int out_size, void* d_ws, size_t ws_size,
                              hipStream_t stream) {
  const float* x     = (const float*)d_in[0];
  const float* t_emb = (const float*)d_in[1];
  const float* swr   = (const float*)d_in[2];
  const float* swi   = (const float*)d_in[3];
  const float* dre   = (const float*)d_in[4];
  const float* dim_  = (const float*)d_in[5];
  const float* ck    = (const float*)d_in[6];
  const float* cbias = (const float*)d_in[7];
  const float* tw    = (const float*)d_in[8];
  const float* pk    = (const float*)d_in[9];
  const float* bns   = (const float*)d_in[10];
  const float* bnb   = (const float*)d_in[11];
  float* ws  = (float*)d_ws;
  float* out = (float*)d_out;

  k_tblA<<<2048, 256, 0, stream>>>(ws);
  k_tblB<<<2560, 256, 0, stream>>>(ws);
  k_dft<<<512, 320, 0, stream>>>(x, ws, out);           // partials into d_out
  k_red1<<<dim3(17, 32), 256, 0, stream>>>(out, ws);    // -> SRED
  k_small<<<32, 256, 0, stream>>>(t_emb, dre, dim_, pk, ws);
  k_spec<<<33, 256, 0, stream>>>(swr, swi, ws);
  k_m2<<<32, 256, 0, stream>>>(ck, cbias, tw, ws);
  k_main<<<2048, 256, 0, stream>>>(x, ws, out);         // overwrites d_out
  k_red<<<1, 1024, 0, stream>>>(ws);
  k_apply<<<2048, 256, 0, stream>>>(out, ws, bns, bnb);
}

// Round 5
// 125.410 us; speedup vs baseline: 5.1461x; 1.4946x over previous
//
#include <hip/hip_runtime.h>

typedef short short8 __attribute__((ext_vector_type(8)));
typedef float f32x4 __attribute__((ext_vector_type(4)));
typedef unsigned short u16;
typedef unsigned int u32;

#define BB 32
#define LL 8192
#define TE 256
#define MM 33
#define INVL (1.0f/8192.0f)
#define TWOPI 6.28318530717958647692f

// ws float offsets
#define TBLM_OFF 0               // Tb bf16 [8192][64]
#define TTD_OFF  262144          // Tt bf16 [80][8192]
#define VTB_OFF  589824          // Vtb bf16 [32][64][128]
#define DD_OFF   720896          // f32 [32][64]  (M2-branch bias)
#define DD2_OFF  722944          // f32 [32][64]  (cos0 spectral bias)
#define PSI_OFF  724992          // f32 [32][128]
#define TC_OFF   729088          // f32 [32][66]  (tcr[33], tci[33])
#define PS_OFF   731200          // f32 [2048][128] BN partials; SRED aliases this
#define SRED_OFF PS_OFF          // f32 [32][65][64] (dead before k_main)
#define MV_OFF   993344          // mean[64], istd[64]
#define PS2_OFF  993472          // f32 [128][128] stage-1 reduced partials

// d_out used as scratch for DFT partials: [32][16][80][64] f32

static __device__ __forceinline__ u16 f2b(float f) {
  u32 u = __float_as_uint(f);
  return (u16)((u + 0x7FFFu + ((u >> 16) & 1u)) >> 16);   // RNE f32->bf16
}

// slot convention (j in 0..63): j=0: sin(m=32); j=1..32: cos(m=j); j=33..63: sin(m=j-32)
static __device__ __forceinline__ float slot_val(int j, int l) {
  int m = (j == 0) ? 32 : (j <= 32 ? j : j - 32);
  bool is_sin = (j == 0) || (j >= 33);
  int r = (m * l) & (LL - 1);
  float ang = (float)r * (TWOPI / (float)LL);
  return is_sin ? sinf(ang) : cosf(ang);
}

// ---------------------------------------------------------------------------
__global__ __launch_bounds__(256) void k_tblA(float* __restrict__ ws) {
  int idx = blockIdx.x * 256 + threadIdx.x;   // < 8192*64
  int l = idx >> 6, j = idx & 63;
  ((u16*)ws)[TBLM_OFF * 2 + idx] = f2b(slot_val(j, l));
}

__global__ __launch_bounds__(256) void k_tblB(float* __restrict__ ws) {
  int j = blockIdx.x >> 5;                    // 0..79
  int l = (blockIdx.x & 31) * 256 + threadIdx.x;
  float v = (j < 64) ? slot_val(j, l) : (j == 64 ? 1.0f : 0.0f);
  ((u16*)ws)[TTD_OFF * 2 + j * LL + l] = f2b(v);
}

// ---------------------------------------------------------------------------
// Phase A: S[b][slot][ch] partials via MFMA.  512 blocks x 320 threads.
__global__ __launch_bounds__(320) void k_dft(const float* __restrict__ x,
                                             const float* __restrict__ ws,
                                             float* __restrict__ scr) {
  __shared__ __align__(16) u16 sX[64 * 136];   // [ch][l'] transposed bf16
  int tid = threadIdx.x;
  int b = blockIdx.x >> 4, chunk = blockIdx.x & 15;
  int l0 = chunk * 512;
  int w = tid >> 6, lane = tid & 63;
  const u16* tt = (const u16*)ws + TTD_OFF * 2;

  f32x4 acc[4];
#pragma unroll
  for (int ct = 0; ct < 4; ++ct) acc[ct] = (f32x4){0.f, 0.f, 0.f, 0.f};

  int arow = lane & 15;
  int kb = (lane >> 4) * 8;

  for (int t = 0; t < 4; ++t) {
    int lt0 = l0 + t * 128;
    __syncthreads();
    for (int p = tid; p < 8192; p += 320) {
      int l = p >> 6, c = p & 63;
      sX[c * 136 + l] = f2b(x[(b * LL + lt0 + l) * 64 + c]);
    }
    __syncthreads();
#pragma unroll
    for (int kk = 0; kk < 4; ++kk) {
      short8 a = *reinterpret_cast<const short8*>(
          tt + (w * 16 + arow) * LL + lt0 + kk * 32 + kb);
#pragma unroll
      for (int ct = 0; ct < 4; ++ct) {
        short8 bf = *reinterpret_cast<const short8*>(&sX[(ct * 16 + arow) * 136 + kk * 32 + kb]);
        acc[ct] = __builtin_amdgcn_mfma_f32_16x16x32_bf16(a, bf, acc[ct], 0, 0, 0);
      }
    }
  }

  int rowb = (lane >> 4) * 4;
#pragma unroll
  for (int ct = 0; ct < 4; ++ct) {
    int ch = ct * 16 + (lane & 15);
#pragma unroll
    for (int r = 0; r < 4; ++r) {
      int sl = w * 16 + rowb + r;
      scr[((b * 16 + chunk) * 80 + sl) * 64 + ch] = acc[ct][r];
    }
  }
}

// ---------------------------------------------------------------------------
// Reduce DFT partials over 16 chunks -> SRED[b][65][64].
__global__ __launch_bounds__(256) void k_red1(const float* __restrict__ scr,
                                              float* __restrict__ ws) {
  int b = blockIdx.y;
  int r = blockIdx.x * 256 + threadIdx.x;     // sl*64+i
  if (r >= 65 * 64) return;
  float a = 0.f;
#pragma unroll
  for (int ch = 0; ch < 16; ++ch) a += scr[(b * 16 + ch) * 5120 + r];
  ws[SRED_OFF + b * 4160 + r] = a;
}

// ---------------------------------------------------------------------------
// psi = t_emb @ psi_kernel ; t_c = t_emb @ dense_{re,im}.  32 blocks.
__global__ __launch_bounds__(256) void k_small(const float* __restrict__ t_emb,
                                               const float* __restrict__ dre,
                                               const float* __restrict__ dim_,
                                               const float* __restrict__ pk,
                                               float* __restrict__ ws) {
  __shared__ float sT[TE];
  int tid = threadIdx.x, b = blockIdx.x;
  sT[tid] = t_emb[b * TE + tid];
  __syncthreads();
  if (tid < 128) {
    float a = 0.f;
#pragma unroll 8
    for (int j = 0; j < TE; ++j) a = fmaf(sT[j], pk[j * 128 + tid], a);
    ws[PSI_OFF + b * 128 + tid] = a;
  } else if (tid < 128 + 66) {
    int tt = tid - 128;
    int m = (tt < 33) ? tt : tt - 33;
    const float* dd = (tt < 33) ? dre : dim_;
    float a = 0.f;
#pragma unroll 8
    for (int j = 0; j < TE; ++j) a = fmaf(sT[j], dd[j * MM + m], a);
    ws[TC_OFF + b * 66 + tt] = a;
  }
}

// ---------------------------------------------------------------------------
// Spectral contraction, one block per mode m (33 blocks x 256).
__global__ __launch_bounds__(256) void k_spec(const float* __restrict__ swr,
                                              const float* __restrict__ swi,
                                              float* __restrict__ ws) {
  __shared__ float2 sW[64 * 64];   // [i][o] (re,im)
  __shared__ float2 sX[32 * 64];   // [b][i] (re,im)
  __shared__ float sTcb[64];       // tcr[32], tci[32]
  int tid = threadIdx.x, m = blockIdx.x;

  for (int idx = tid; idx < 4096; idx += 256) {
    float wr = swr[m * 4096 + idx];
    float wi = swi[m * 4096 + idx];
    sW[idx] = make_float2(wr, wi);
  }
  for (int idx = tid; idx < 2048; idx += 256) {
    int b = idx >> 6, i = idx & 63;
    const float* sr = ws + SRED_OFF + b * 4160;
    float xr, xi;
    if (m == 0)      { xr = sr[64 * 64 + i] * INVL;      xi = 0.f; }
    else if (m < 32) { xr = sr[m * 64 + i] * INVL;       xi = -sr[(32 + m) * 64 + i] * INVL; }
    else             { xr = sr[32 * 64 + i] * INVL;      xi = -sr[0 * 64 + i] * INVL; }
    sX[idx] = make_float2(xr, xi);
  }
  if (tid < 64) {
    int b = tid & 31, half = tid >> 5;
    sTcb[tid] = ws[TC_OFF + b * 66 + half * 33 + m];
  }
  __syncthreads();

  int w = tid >> 6, lane = tid & 63;
  for (int p = 0; p < 8; ++p) {
    int b = p * 4 + w;
    float a0 = 0.f, a1 = 0.f, a2 = 0.f, a3 = 0.f;
#pragma unroll 16
    for (int i = 0; i < 64; ++i) {
      float2 wv = sW[i * 64 + lane];
      float2 xv = sX[b * 64 + i];
      a0 = fmaf(xv.x, wv.x, a0);
      a1 = fmaf(xv.y, wv.y, a1);
      a2 = fmaf(xv.x, wv.y, a2);
      a3 = fmaf(xv.y, wv.x, a3);
    }
    float ar = a0 - a1, ai = a2 + a3;
    float tcr = sTcb[b], tci = sTcb[32 + b];
    float cr = tcr * ar - tci * ai;
    float ci = tcr * ai + tci * ar;
    if (m == 0) {
      ws[DD2_OFF + b * 64 + lane] = cr;
    } else {
      u16* vtb = (u16*)ws + VTB_OFF * 2 + (b * 64 + lane) * 128;
      vtb[64 + m] = f2b(2.f * cr);
      vtb[64 + ((m == 32) ? 0 : 32 + m)] = f2b(-2.f * ci);
    }
  }
}

// ---------------------------------------------------------------------------
// M2[b][c][o] = sum_j ck[c,j] psi[b,j] tw[o,j] -> V rows 0..63; D1[b][o].
__global__ __launch_bounds__(256) void k_m2(const float* __restrict__ ck,
                                            const float* __restrict__ cbias,
                                            const float* __restrict__ tw,
                                            float* __restrict__ ws) {
  __shared__ float sCkT[64 * 64];   // [j][c]
  __shared__ float sPtw[64 * 64];   // [o][j] = psi[j]*tw[o][j]
  __shared__ float sPsi[128];
  int tid = threadIdx.x, b = blockIdx.x;

  if (tid < 128) sPsi[tid] = ws[PSI_OFF + b * 128 + tid];
  __syncthreads();
  for (int idx = tid; idx < 4096; idx += 256) {
    int c = idx >> 6, j = idx & 63;
    sCkT[j * 64 + c] = ck[idx];
    sPtw[idx] = sPsi[j] * tw[idx];     // idx = o*64+j
  }
  __syncthreads();

  u16* vtb = (u16*)ws + VTB_OFF * 2 + b * 64 * 128;
  int lane = tid & 63, w = tid >> 6;
#pragma unroll 4
  for (int it = 0; it < 16; ++it) {
    int o = it * 4 + w;              // wave-uniform
    float a = 0.f;
#pragma unroll 16
    for (int j = 0; j < 64; ++j)
      a = fmaf(sCkT[j * 64 + lane], sPtw[o * 64 + j], a);
    vtb[o * 128 + lane] = f2b(a);
  }
  if (tid < 64) {
    float a = 0.f;
    for (int j = 0; j < 64; ++j) a = fmaf(cbias[j], sPtw[tid * 64 + j], a);
    ws[DD_OFF + b * 64 + tid] = a + sPsi[64 + tid];
  }
}

// ---------------------------------------------------------------------------
// Phase C: out_pre = U(8192x128) @ V[b](128x64) + D[b] via MFMA, fused BN stats.
__global__ __launch_bounds__(256) void k_main(const float* __restrict__ x,
                                              float* __restrict__ ws,
                                              float* __restrict__ out) {
  __shared__ __align__(16) u16 sVt[64 * 136];
  __shared__ float sD[64];
  __shared__ float sRed[4 * 128];
  int tid = threadIdx.x, w = tid >> 6, lane = tid & 63;
  int b = blockIdx.x >> 6, rg = blockIdx.x & 63;
  const u16* wsu = (const u16*)ws;

  {
    const u32* src = (const u32*)(wsu + VTB_OFF * 2 + b * 64 * 128);
    u32* dst = (u32*)sVt;
    for (int p = tid; p < 4096; p += 256)
      dst[(p >> 6) * 68 + (p & 63)] = src[p];
  }
  if (tid < 64) sD[tid] = ws[DD_OFF + b * 64 + tid] + ws[DD2_OFF + b * 64 + tid];
  __syncthreads();

  int kb = (lane >> 4) * 8;
  short8 bf[4][4];
#pragma unroll
  for (int kk = 0; kk < 4; ++kk)
#pragma unroll
    for (int ct = 0; ct < 4; ++ct)
      bf[kk][ct] = *reinterpret_cast<const short8*>(
          &sVt[(ct * 16 + (lane & 15)) * 136 + kk * 32 + kb]);

  const u16* tb = wsu + TBLM_OFF * 2;
  float s1[4] = {0.f, 0.f, 0.f, 0.f}, s2[4] = {0.f, 0.f, 0.f, 0.f};
  int rowb = (lane >> 4) * 4;
  int lbase = rg * 128 + w * 32;

#pragma unroll
  for (int rt = 0; rt < 2; ++rt) {
    int l = lbase + rt * 16 + (lane & 15);
    const float* xq = x + (b * LL + l) * 64;
    float4 u0 = *reinterpret_cast<const float4*>(xq + kb);
    float4 u1 = *reinterpret_cast<const float4*>(xq + kb + 4);
    float4 u2 = *reinterpret_cast<const float4*>(xq + 32 + kb);
    float4 u3 = *reinterpret_cast<const float4*>(xq + 32 + kb + 4);
    short8 a0, a1;
    a0[0] = (short)f2b(u0.x); a0[1] = (short)f2b(u0.y);
    a0[2] = (short)f2b(u0.z); a0[3] = (short)f2b(u0.w);
    a0[4] = (short)f2b(u1.x); a0[5] = (short)f2b(u1.y);
    a0[6] = (short)f2b(u1.z); a0[7] = (short)f2b(u1.w);
    a1[0] = (short)f2b(u2.x); a1[1] = (short)f2b(u2.y);
    a1[2] = (short)f2b(u2.z); a1[3] = (short)f2b(u2.w);
    a1[4] = (short)f2b(u3.x); a1[5] = (short)f2b(u3.y);
    a1[6] = (short)f2b(u3.z); a1[7] = (short)f2b(u3.w);
    short8 a2 = *reinterpret_cast<const short8*>(tb + l * 64 + kb);
    short8 a3 = *reinterpret_cast<const short8*>(tb + l * 64 + 32 + kb);

    f32x4 acc[4];
#pragma unroll
    for (int ct = 0; ct < 4; ++ct) acc[ct] = (f32x4){0.f, 0.f, 0.f, 0.f};
#pragma unroll
    for (int ct = 0; ct < 4; ++ct) {
      acc[ct] = __builtin_amdgcn_mfma_f32_16x16x32_bf16(a0, bf[0][ct], acc[ct], 0, 0, 0);
      acc[ct] = __builtin_amdgcn_mfma_f32_16x16x32_bf16(a1, bf[1][ct], acc[ct], 0, 0, 0);
      acc[ct] = __builtin_amdgcn_mfma_f32_16x16x32_bf16(a2, bf[2][ct], acc[ct], 0, 0, 0);
      acc[ct] = __builtin_amdgcn_mfma_f32_16x16x32_bf16(a3, bf[3][ct], acc[ct], 0, 0, 0);
    }
#pragma unroll
    for (int ct = 0; ct < 4; ++ct) {
      int o = ct * 16 + (lane & 15);
      float dd = sD[o];
#pragma unroll
      for (int r = 0; r < 4; ++r) {
        float v = acc[ct][r] + dd;
        out[(b * LL + lbase + rt * 16 + rowb + r) * 64 + o] = v;
        s1[ct] += v;
        s2[ct] = fmaf(v, v, s2[ct]);
      }
    }
  }

#pragma unroll
  for (int ct = 0; ct < 4; ++ct) {
    s1[ct] += __shfl_xor(s1[ct], 16); s1[ct] += __shfl_xor(s1[ct], 32);
    s2[ct] += __shfl_xor(s2[ct], 16); s2[ct] += __shfl_xor(s2[ct], 32);
  }
  if (lane < 16) {
#pragma unroll
    for (int ct = 0; ct < 4; ++ct) {
      sRed[w * 128 + ct * 16 + lane] = s1[ct];
      sRed[w * 128 + 64 + ct * 16 + lane] = s2[ct];
    }
  }
  __syncthreads();
  if (tid < 128) {
    float t = sRed[tid] + sRed[128 + tid] + sRed[256 + tid] + sRed[384 + tid];
    ws[PS_OFF + blockIdx.x * 128 + tid] = t;
  }
}

// ---------------------------------------------------------------------------
// BN reduction stage 1: 128 blocks x 256; block reduces 16 PS rows -> PS2.
__global__ __launch_bounds__(256) void k_redA(float* __restrict__ ws) {
  __shared__ float sr[256];
  int tid = threadIdx.x;
  int c = tid & 127, h = tid >> 7;            // h in {0,1}
  int r0 = blockIdx.x * 16 + h * 8;
  float a = 0.f;
#pragma unroll
  for (int r = 0; r < 8; ++r)
    a += ws[PS_OFF + (r0 + r) * 128 + c];
  sr[tid] = a;
  __syncthreads();
  if (tid < 128)
    ws[PS2_OFF + blockIdx.x * 128 + tid] = sr[tid] + sr[128 + tid];
}

// BN reduction stage 2: 1 block x 256; 64 KB read, unrolled independent loads.
__global__ __launch_bounds__(256) void k_redB(float* __restrict__ ws) {
  __shared__ float sr[256];
  int tid = threadIdx.x;
  int c = tid & 127, h = tid >> 7;
  float a = 0.f;
#pragma unroll 8
  for (int r = h * 64; r < h * 64 + 64; ++r)
    a += ws[PS2_OFF + r * 128 + c];
  sr[tid] = a;
  __syncthreads();
  if (tid < 64) {
    const float inv_n = 1.f / ((float)BB * (float)LL);
    float mean = (sr[tid] + sr[128 + tid]) * inv_n;
    float ex2 = (sr[64 + tid] + sr[192 + tid]) * inv_n;
    float var = ex2 - mean * mean;
    ws[MV_OFF + tid] = mean;
    ws[MV_OFF + 64 + tid] = rsqrtf(var + 1e-5f);
  }
}

// ---------------------------------------------------------------------------
__global__ __launch_bounds__(256) void k_apply(float* __restrict__ out,
                                               const float* __restrict__ ws,
                                               const float* __restrict__ bns,
                                               const float* __restrict__ bnb) {
  int gid = blockIdx.x * 256 + threadIdx.x;
  int c4 = gid & 15;
  const float4 mean = *reinterpret_cast<const float4*>(ws + MV_OFF + 4 * c4);
  const float4 istd = *reinterpret_cast<const float4*>(ws + MV_OFF + 64 + 4 * c4);
  const float4 sc   = *reinterpret_cast<const float4*>(bns + 4 * c4);
  const float4 bi   = *reinterpret_cast<const float4*>(bnb + 4 * c4);
  float4* po = reinterpret_cast<float4*>(out);
#pragma unroll
  for (int it = 0; it < 8; ++it) {
    int i4 = gid + it * 524288;
    float4 v = po[i4];
    v.x = fmaxf(fmaf((v.x - mean.x) * istd.x, sc.x, bi.x), 0.f);
    v.y = fmaxf(fmaf((v.y - mean.y) * istd.y, sc.y, bi.y), 0.f);
    v.z = fmaxf(fmaf((v.z - mean.z) * istd.z, sc.z, bi.z), 0.f);
    v.w = fmaxf(fmaf((v.w - mean.w) * istd.w, sc.w, bi.w), 0.f);
    po[i4] = v;
  }
}

// ---------------------------------------------------------------------------
extern "C" void kernel_launch(void* const* d_in, const int* in_sizes, int n_in,
                              void* d_out, int out_size, void* d_ws, size_t ws_size,
                              hipStream_t stream) {
  const float* x     = (const float*)d_in[0];
  const float* t_emb = (const float*)d_in[1];
  const float* swr   = (const float*)d_in[2];
  const float* swi   = (const float*)d_in[3];
  const float* dre   = (const float*)d_in[4];
  const float* dim_  = (const float*)d_in[5];
  const float* ck    = (const float*)d_in[6];
  const float* cbias = (const float*)d_in[7];
  const float* tw    = (const float*)d_in[8];
  const float* pk    = (const float*)d_in[9];
  const float* bns   = (const float*)d_in[10];
  const float* bnb   = (const float*)d_in[11];
  float* ws  = (float*)d_ws;
  float* out = (float*)d_out;

  k_tblA<<<2048, 256, 0, stream>>>(ws);
  k_tblB<<<2560, 256, 0, stream>>>(ws);
  k_dft<<<512, 320, 0, stream>>>(x, ws, out);           // partials into d_out
  k_red1<<<dim3(17, 32), 256, 0, stream>>>(out, ws);    // -> SRED
  k_small<<<32, 256, 0, stream>>>(t_emb, dre, dim_, pk, ws);
  k_spec<<<33, 256, 0, stream>>>(swr, swi, ws);
  k_m2<<<32, 256, 0, stream>>>(ck, cbias, tw, ws);
  k_main<<<2048, 256, 0, stream>>>(x, ws, out);         // overwrites d_out
  k_redA<<<128, 256, 0, stream>>>(ws);
  k_redB<<<1, 256, 0, stream>>>(ws);
  k_apply<<<2048, 256, 0, stream>>>(out, ws, bns, bnb);
}

// Round 6
// 120.080 us; speedup vs baseline: 5.3745x; 1.0444x over previous
//
#include <hip/hip_runtime.h>

typedef short short8 __attribute__((ext_vector_type(8)));
typedef float f32x4 __attribute__((ext_vector_type(4)));
typedef unsigned short u16;
typedef unsigned int u32;

#define BB 32
#define LL 8192
#define TE 256
#define MM 33
#define INVL (1.0f/8192.0f)
#define TWOPI 6.28318530717958647692f

// ---- ws float offsets ----
#define TBLM_OFF 0               // Tb bf16 [8192][64]
#define TTD_OFF  262144          // Tt bf16 [80][8192]
#define VTB_OFF  589824          // Vtb bf16 [32][64][128] (V^T for k_main)
#define DD_OFF   720896          // f32 [32][64]  (M2-branch bias)
#define DD2_OFF  722944          // f32 [32][64]  (cos0 spectral bias)
#define PSI_OFF  724992          // f32 [32][128]
#define TC_OFF   729088          // f32 [32][66]
#define BNP_OFF  731200          // f32 [32][2][64] per-batch BN partials
#define MV_OFF   735296          // alpha[64], beta[64]

// ---- d_out (scr) float offsets; all dead before k_main overwrites ----
#define PART_OFF  0              // [b][chunk16][144][64] DFT+Gram partials
#define SRED2_OFF 4718592        // [b][144][64] chunk-reduced (rows 0..63 slots,
                                 //  64 = plain sum, 80..143 = Gx)
#define VF_OFF    5013504        // f32 V [b][128][64] (k-major, for k_bn)

static __device__ __forceinline__ u16 f2b(float f) {
  u32 u = __float_as_uint(f);
  return (u16)((u + 0x7FFFu + ((u >> 16) & 1u)) >> 16);   // RNE f32->bf16
}
// round-half-up bf16 (2 VALU ops) for hot paths
static __device__ __forceinline__ u16 f2bh(float f) {
  return (u16)((__float_as_uint(f) + 0x8000u) >> 16);
}
// pack two floats -> two bf16 (half-up) via v_perm
static __device__ __forceinline__ u32 pk2(float lo, float hi) {
  return __builtin_amdgcn_perm(__float_as_uint(hi) + 0x8000u,
                               __float_as_uint(lo) + 0x8000u,
                               0x07060302u);
}

// slot j: j=0 -> sin(m=32); j=1..32 -> cos(m=j); j=33..63 -> sin(m=j-32)
static __device__ __forceinline__ float slot_val(int j, int l) {
  int m = (j == 0) ? 32 : (j <= 32 ? j : j - 32);
  bool is_sin = (j == 0) || (j >= 33);
  int r = (m * l) & (LL - 1);
  float ang = (float)r * (TWOPI / (float)LL);
  return is_sin ? sinf(ang) : cosf(ang);
}

// ---------------------------------------------------------------------------
__global__ __launch_bounds__(256) void k_tblA(float* __restrict__ ws) {
  int idx = blockIdx.x * 256 + threadIdx.x;   // < 8192*64
  int l = idx >> 6, j = idx & 63;
  ((u16*)ws)[TBLM_OFF * 2 + idx] = f2b(slot_val(j, l));
}

__global__ __launch_bounds__(256) void k_tblB(float* __restrict__ ws) {
  int j = blockIdx.x >> 5;                    // 0..79
  int l = (blockIdx.x & 31) * 256 + threadIdx.x;
  float v = (j < 64) ? slot_val(j, l) : (j == 64 ? 1.0f : 0.0f);
  ((u16*)ws)[TTD_OFF * 2 + j * LL + l] = f2b(v);
}

// ---------------------------------------------------------------------------
// Phase A: DFT partials (80 rows) + Gram x^Tx partials (64 rows) via MFMA.
// 512 blocks x 576 threads (9 waves): waves 0..4 -> slot rows (A from table),
// waves 5..8 -> Gram rows (A from the same LDS x-tile).
__global__ __launch_bounds__(576) void k_dft(const float* __restrict__ x,
                                             const float* __restrict__ ws,
                                             float* __restrict__ scr) {
  __shared__ __align__(16) u16 sX[64 * 136];   // [ch][l'] transposed bf16
  int tid = threadIdx.x;
  int b = blockIdx.x >> 4, chunk = blockIdx.x & 15;
  int l0 = chunk * 512;
  int w = tid >> 6, lane = tid & 63;
  const u16* tt = (const u16*)ws + TTD_OFF * 2;

  f32x4 acc[4];
#pragma unroll
  for (int ct = 0; ct < 4; ++ct) acc[ct] = (f32x4){0.f, 0.f, 0.f, 0.f};

  int arow = lane & 15;
  int kb = (lane >> 4) * 8;
  bool isg = (w >= 5);
  int gi = w - 5;

  for (int t = 0; t < 4; ++t) {
    int lt0 = l0 + t * 128;
    __syncthreads();
    for (int p = tid; p < 8192; p += 576) {
      int l = p >> 6, c = p & 63;
      sX[c * 136 + l] = f2bh(x[(b * LL + lt0 + l) * 64 + c]);
    }
    __syncthreads();
#pragma unroll
    for (int kk = 0; kk < 4; ++kk) {
      short8 a = isg
        ? *reinterpret_cast<const short8*>(&sX[(gi * 16 + arow) * 136 + kk * 32 + kb])
        : *reinterpret_cast<const short8*>(tt + (w * 16 + arow) * LL + lt0 + kk * 32 + kb);
#pragma unroll
      for (int ct = 0; ct < 4; ++ct) {
        short8 bf = *reinterpret_cast<const short8*>(&sX[(ct * 16 + arow) * 136 + kk * 32 + kb]);
        acc[ct] = __builtin_amdgcn_mfma_f32_16x16x32_bf16(a, bf, acc[ct], 0, 0, 0);
      }
    }
  }

  int rowbase = isg ? (80 + gi * 16) : (w * 16);
  int rowb = (lane >> 4) * 4;
#pragma unroll
  for (int ct = 0; ct < 4; ++ct) {
    int col = ct * 16 + (lane & 15);
#pragma unroll
    for (int r = 0; r < 4; ++r)
      scr[PART_OFF + ((b * 16 + chunk) * 144 + rowbase + rowb + r) * 64 + col] = acc[ct][r];
  }
}

// ---------------------------------------------------------------------------
// Reduce partials over 16 chunks -> SRED2[b][144][64].  grid (36, 32).
__global__ __launch_bounds__(256) void k_red1(float* __restrict__ scr) {
  int b = blockIdx.y;
  int r = blockIdx.x * 256 + threadIdx.x;     // < 9216
  float a = 0.f;
#pragma unroll
  for (int ch = 0; ch < 16; ++ch) a += scr[PART_OFF + (b * 16 + ch) * 9216 + r];
  scr[SRED2_OFF + b * 9216 + r] = a;
}

// ---------------------------------------------------------------------------
// psi = t_emb @ psi_kernel ; t_c = t_emb @ dense_{re,im}.  32 blocks.
__global__ __launch_bounds__(256) void k_small(const float* __restrict__ t_emb,
                                               const float* __restrict__ dre,
                                               const float* __restrict__ dim_,
                                               const float* __restrict__ pk,
                                               float* __restrict__ ws) {
  __shared__ float sT[TE];
  int tid = threadIdx.x, b = blockIdx.x;
  sT[tid] = t_emb[b * TE + tid];
  __syncthreads();
  if (tid < 128) {
    float a = 0.f;
#pragma unroll 8
    for (int j = 0; j < TE; ++j) a = fmaf(sT[j], pk[j * 128 + tid], a);
    ws[PSI_OFF + b * 128 + tid] = a;
  } else if (tid < 128 + 66) {
    int tt = tid - 128;
    int m = (tt < 33) ? tt : tt - 33;
    const float* dd = (tt < 33) ? dre : dim_;
    float a = 0.f;
#pragma unroll 8
    for (int j = 0; j < TE; ++j) a = fmaf(sT[j], dd[j * MM + m], a);
    ws[TC_OFF + b * 66 + tt] = a;
  }
}

// ---------------------------------------------------------------------------
// Spectral contraction, one block per mode m (33 blocks x 256).
// Writes bf16 V^T rows (ws) AND f32 V[k][o] (scr, for k_bn).
__global__ __launch_bounds__(256) void k_spec(const float* __restrict__ swr,
                                              const float* __restrict__ swi,
                                              float* __restrict__ scr,
                                              float* __restrict__ ws) {
  __shared__ float2 sW[64 * 64];   // [i][o] (re,im)
  __shared__ float2 sX[32 * 64];   // [b][i] (re,im)
  __shared__ float sTcb[64];
  int tid = threadIdx.x, m = blockIdx.x;

  for (int idx = tid; idx < 4096; idx += 256)
    sW[idx] = make_float2(swr[m * 4096 + idx], swi[m * 4096 + idx]);
  for (int idx = tid; idx < 2048; idx += 256) {
    int b = idx >> 6, i = idx & 63;
    const float* sr = scr + SRED2_OFF + b * 9216;
    float xr, xi;
    if (m == 0)      { xr = sr[64 * 64 + i] * INVL;  xi = 0.f; }
    else if (m < 32) { xr = sr[m * 64 + i] * INVL;   xi = -sr[(32 + m) * 64 + i] * INVL; }
    else             { xr = sr[32 * 64 + i] * INVL;  xi = -sr[0 * 64 + i] * INVL; }
    sX[idx] = make_float2(xr, xi);
  }
  if (tid < 64) {
    int b = tid & 31, half = tid >> 5;
    sTcb[tid] = ws[TC_OFF + b * 66 + half * 33 + m];
  }
  __syncthreads();

  int w = tid >> 6, lane = tid & 63;
  for (int p = 0; p < 8; ++p) {
    int b = p * 4 + w;
    float a0 = 0.f, a1 = 0.f, a2 = 0.f, a3 = 0.f;
#pragma unroll 16
    for (int i = 0; i < 64; ++i) {
      float2 wv = sW[i * 64 + lane];
      float2 xv = sX[b * 64 + i];
      a0 = fmaf(xv.x, wv.x, a0);
      a1 = fmaf(xv.y, wv.y, a1);
      a2 = fmaf(xv.x, wv.y, a2);
      a3 = fmaf(xv.y, wv.x, a3);
    }
    float ar = a0 - a1, ai = a2 + a3;
    float tcr = sTcb[b], tci = sTcb[32 + b];
    float cr = tcr * ar - tci * ai;
    float ci = tcr * ai + tci * ar;
    if (m == 0) {
      ws[DD2_OFF + b * 64 + lane] = cr;
    } else {
      float crr = 2.f * cr, cii = -2.f * ci;
      int js = (m == 32) ? 0 : 32 + m;
      u16* vtb = (u16*)ws + VTB_OFF * 2 + (b * 64 + lane) * 128;
      vtb[64 + m] = f2b(crr);
      vtb[64 + js] = f2b(cii);
      float* vf = scr + VF_OFF + b * 8192;
      vf[(64 + m) * 64 + lane] = crr;
      vf[(64 + js) * 64 + lane] = cii;
    }
  }
}

// ---------------------------------------------------------------------------
// M2[b][c][o] = sum_j ck[c,j] psi[b,j] tw[o,j] -> V rows 0..63; D1[b][o].
__global__ __launch_bounds__(256) void k_m2(const float* __restrict__ ck,
                                            const float* __restrict__ cbias,
                                            const float* __restrict__ tw,
                                            float* __restrict__ scr,
                                            float* __restrict__ ws) {
  __shared__ float sCkT[64 * 64];   // [j][c]
  __shared__ float sPtw[64 * 64];   // [o][j]
  __shared__ float sPsi[128];
  int tid = threadIdx.x, b = blockIdx.x;

  if (tid < 128) sPsi[tid] = ws[PSI_OFF + b * 128 + tid];
  __syncthreads();
  for (int idx = tid; idx < 4096; idx += 256) {
    int c = idx >> 6, j = idx & 63;
    sCkT[j * 64 + c] = ck[idx];
    sPtw[idx] = sPsi[j] * tw[idx];
  }
  __syncthreads();

  u16* vtb = (u16*)ws + VTB_OFF * 2 + b * 64 * 128;
  float* vf = scr + VF_OFF + b * 8192;
  int lane = tid & 63, w = tid >> 6;
#pragma unroll 4
  for (int it = 0; it < 16; ++it) {
    int o = it * 4 + w;
    float a = 0.f;
#pragma unroll 16
    for (int j = 0; j < 64; ++j)
      a = fmaf(sCkT[j * 64 + lane], sPtw[o * 64 + j], a);
    vtb[o * 128 + lane] = f2b(a);
    vf[lane * 64 + o] = a;
  }
  if (tid < 64) {
    float a = 0.f;
    for (int j = 0; j < 64; ++j) a = fmaf(cbias[j], sPtw[tid * 64 + j], a);
    ws[DD_OFF + b * 64 + tid] = a + sPsi[64 + tid];
  }
}

// ---------------------------------------------------------------------------
// Analytic BN partials per batch:
//   SigP[o]   = sum_i Ssum[i] Vx[i,o]                      (table cols sum to 0)
//   SigP2[o]  = Vx^T Gx Vx + 2*sum_js Vt[js,o](S Vx) + (L/2)|Vt|^2
//   BNP[b][0] = SigP + L*D ; BNP[b][1] = SigP2 + 2 D SigP + L D^2
__global__ __launch_bounds__(256) void k_bn(const float* __restrict__ scr,
                                            float* __restrict__ ws) {
  __shared__ float sVx[64 * 64];
  __shared__ float sGx[64 * 64];
  __shared__ float sS[64 * 64];
  __shared__ float sSum[64];
  __shared__ float sP[4][2][64];
  int tid = threadIdx.x, b = blockIdx.x;
  const float* sr = scr + SRED2_OFF + b * 9216;
  const float* vf = scr + VF_OFF + b * 8192;

  for (int p = tid; p < 4096; p += 256) {
    sVx[p] = vf[p];              // V rows 0..63
    sGx[p] = sr[80 * 64 + p];    // Gram rows
    sS[p]  = sr[p];              // slot rows 0..63
  }
  if (tid < 64) sSum[tid] = sr[64 * 64 + tid];
  __syncthreads();

  int o = tid & 63, part = tid >> 6;
  float m1 = 0.f, q1 = 0.f, cross = 0.f, vt2 = 0.f;
  for (int ii = 0; ii < 16; ++ii) {
    int i = part * 16 + ii;
    float vx = sVx[i * 64 + o];
    m1 = fmaf(sSum[i], vx, m1);
    float w0 = 0.f, w1 = 0.f, c0 = 0.f, c1 = 0.f;
#pragma unroll
    for (int j = 0; j < 64; j += 2) {
      float va = sVx[j * 64 + o], vb = sVx[(j + 1) * 64 + o];
      w0 = fmaf(sGx[i * 64 + j], va, w0);
      w1 = fmaf(sGx[i * 64 + j + 1], vb, w1);
      c0 = fmaf(sS[i * 64 + j], va, c0);
      c1 = fmaf(sS[i * 64 + j + 1], vb, c1);
    }
    q1 = fmaf(vx, w0 + w1, q1);
    float vt = vf[(64 + i) * 64 + o];
    vt2 = fmaf(vt, vt, vt2);
    cross = fmaf(vt, c0 + c1, cross);
  }
  sP[part][0][o] = m1;
  sP[part][1][o] = q1 + 2.f * cross + 4096.f * vt2;   // L/2 = 4096
  __syncthreads();
  if (tid < 64) {
    float m = sP[0][0][tid] + sP[1][0][tid] + sP[2][0][tid] + sP[3][0][tid];
    float q = sP[0][1][tid] + sP[1][1][tid] + sP[2][1][tid] + sP[3][1][tid];
    float D = ws[DD_OFF + b * 64 + tid] + ws[DD2_OFF + b * 64 + tid];
    ws[BNP_OFF + b * 128 + tid]      = m + 8192.f * D;
    ws[BNP_OFF + b * 128 + 64 + tid] = q + 2.f * D * m + 8192.f * D * D;
  }
}

__global__ __launch_bounds__(64) void k_bn2(const float* __restrict__ bns,
                                            const float* __restrict__ bnb,
                                            float* __restrict__ ws) {
  int o = threadIdx.x;
  float sm = 0.f, sq = 0.f;
#pragma unroll
  for (int b = 0; b < 32; ++b) {
    sm += ws[BNP_OFF + b * 128 + o];
    sq += ws[BNP_OFF + b * 128 + 64 + o];
  }
  const float inv_n = 1.f / (32.f * 8192.f);
  float mean = sm * inv_n;
  float var = sq * inv_n - mean * mean;
  float istd = rsqrtf(var + 1e-5f);
  float alpha = istd * bns[o];
  ws[MV_OFF + o] = alpha;
  ws[MV_OFF + 64 + o] = bnb[o] - mean * alpha;
}

// ---------------------------------------------------------------------------
// Phase C: out = relu(alpha*(U@V + D) + beta) via MFMA.  2048 x 256.
__global__ __launch_bounds__(256) void k_main(const float* __restrict__ x,
                                              const float* __restrict__ ws,
                                              float* __restrict__ out) {
  __shared__ __align__(16) u16 sVt[64 * 136];
  __shared__ float sD[64];
  __shared__ float sA[64];
  __shared__ float sB[64];
  int tid = threadIdx.x, w = tid >> 6, lane = tid & 63;
  int b = blockIdx.x >> 6, rg = blockIdx.x & 63;
  const u16* wsu = (const u16*)ws;

  {
    const u32* src = (const u32*)(wsu + VTB_OFF * 2 + b * 64 * 128);
    u32* dst = (u32*)sVt;
    for (int p = tid; p < 4096; p += 256)
      dst[(p >> 6) * 68 + (p & 63)] = src[p];
  }
  if (tid < 64) {
    sD[tid] = ws[DD_OFF + b * 64 + tid] + ws[DD2_OFF + b * 64 + tid];
    sA[tid] = ws[MV_OFF + tid];
    sB[tid] = ws[MV_OFF + 64 + tid];
  }
  __syncthreads();

  int kb = (lane >> 4) * 8;
  short8 bf[4][4];
#pragma unroll
  for (int kk = 0; kk < 4; ++kk)
#pragma unroll
    for (int ct = 0; ct < 4; ++ct)
      bf[kk][ct] = *reinterpret_cast<const short8*>(
          &sVt[(ct * 16 + (lane & 15)) * 136 + kk * 32 + kb]);

  const u16* tb = wsu + TBLM_OFF * 2;
  int rowb = (lane >> 4) * 4;
  int lbase = rg * 128 + w * 32;

#pragma unroll
  for (int rt = 0; rt < 2; ++rt) {
    int l = lbase + rt * 16 + (lane & 15);
    const float* xq = x + (b * LL + l) * 64;
    float4 u0 = *reinterpret_cast<const float4*>(xq + kb);
    float4 u1 = *reinterpret_cast<const float4*>(xq + kb + 4);
    float4 u2 = *reinterpret_cast<const float4*>(xq + 32 + kb);
    float4 u3 = *reinterpret_cast<const float4*>(xq + 32 + kb + 4);
    union { short8 s; u32 wv[4]; } A0, A1;
    A0.wv[0] = pk2(u0.x, u0.y); A0.wv[1] = pk2(u0.z, u0.w);
    A0.wv[2] = pk2(u1.x, u1.y); A0.wv[3] = pk2(u1.z, u1.w);
    A1.wv[0] = pk2(u2.x, u2.y); A1.wv[1] = pk2(u2.z, u2.w);
    A1.wv[2] = pk2(u3.x, u3.y); A1.wv[3] = pk2(u3.z, u3.w);
    short8 a2 = *reinterpret_cast<const short8*>(tb + l * 64 + kb);
    short8 a3 = *reinterpret_cast<const short8*>(tb + l * 64 + 32 + kb);

    f32x4 acc[4];
#pragma unroll
    for (int ct = 0; ct < 4; ++ct) acc[ct] = (f32x4){0.f, 0.f, 0.f, 0.f};
#pragma unroll
    for (int ct = 0; ct < 4; ++ct) {
      acc[ct] = __builtin_amdgcn_mfma_f32_16x16x32_bf16(A0.s, bf[0][ct], acc[ct], 0, 0, 0);
      acc[ct] = __builtin_amdgcn_mfma_f32_16x16x32_bf16(A1.s, bf[1][ct], acc[ct], 0, 0, 0);
      acc[ct] = __builtin_amdgcn_mfma_f32_16x16x32_bf16(a2, bf[2][ct], acc[ct], 0, 0, 0);
      acc[ct] = __builtin_amdgcn_mfma_f32_16x16x32_bf16(a3, bf[3][ct], acc[ct], 0, 0, 0);
    }
#pragma unroll
    for (int ct = 0; ct < 4; ++ct) {
      int o = ct * 16 + (lane & 15);
      float dd = sD[o], al = sA[o], be = sB[o];
#pragma unroll
      for (int r = 0; r < 4; ++r) {
        float v = acc[ct][r] + dd;
        out[(b * LL + lbase + rt * 16 + rowb + r) * 64 + o] =
            fmaxf(fmaf(v, al, be), 0.f);
      }
    }
  }
}

// ---------------------------------------------------------------------------
extern "C" void kernel_launch(void* const* d_in, const int* in_sizes, int n_in,
                              void* d_out, int out_size, void* d_ws, size_t ws_size,
                              hipStream_t stream) {
  const float* x     = (const float*)d_in[0];
  const float* t_emb = (const float*)d_in[1];
  const float* swr   = (const float*)d_in[2];
  const float* swi   = (const float*)d_in[3];
  const float* dre   = (const float*)d_in[4];
  const float* dim_  = (const float*)d_in[5];
  const float* ck    = (const float*)d_in[6];
  const float* cbias = (const float*)d_in[7];
  const float* tw    = (const float*)d_in[8];
  const float* pk    = (const float*)d_in[9];
  const float* bns   = (const float*)d_in[10];
  const float* bnb   = (const float*)d_in[11];
  float* ws  = (float*)d_ws;
  float* out = (float*)d_out;

  k_tblA<<<2048, 256, 0, stream>>>(ws);
  k_tblB<<<2560, 256, 0, stream>>>(ws);
  k_dft<<<512, 576, 0, stream>>>(x, ws, out);           // partials into d_out
  k_red1<<<dim3(36, 32), 256, 0, stream>>>(out);        // -> SRED2 (in d_out)
  k_small<<<32, 256, 0, stream>>>(t_emb, dre, dim_, pk, ws);
  k_spec<<<33, 256, 0, stream>>>(swr, swi, out, ws);
  k_m2<<<32, 256, 0, stream>>>(ck, cbias, tw, out, ws);
  k_bn<<<32, 256, 0, stream>>>(out, ws);
  k_bn2<<<1, 64, 0, stream>>>(bns, bnb, ws);
  k_main<<<2048, 256, 0, stream>>>(x, ws, out);         // overwrites d_out
}

// Round 7
// 115.844 us; speedup vs baseline: 5.5710x; 1.0366x over previous
//
#include <hip/hip_runtime.h>

typedef short short8 __attribute__((ext_vector_type(8)));
typedef float f32x4 __attribute__((ext_vector_type(4)));
typedef unsigned int u32;
typedef u32 u32x4 __attribute__((ext_vector_type(4)));
typedef unsigned short u16;

#define BB 32
#define LL 8192
#define TE 256
#define MM 33
#define INVL (1.0f/8192.0f)
#define TWOPI 6.28318530717958647692f

// ---- ws float offsets ----
#define TBLM_OFF 0               // Tb bf16 [8192][64]
#define TTD_OFF  262144          // Tt bf16 [80][8192]
#define VTB_OFF  589824          // Vtb bf16 [32][64][128] (V^T for k_main)
#define DD_OFF   720896          // f32 [32][64]  (M2-branch bias)
#define DD2_OFF  722944          // f32 [32][64]  (cos0 spectral bias)
#define PSI_OFF  724992          // f32 [32][128]
#define TC_OFF   729088          // f32 [32][66]
#define BNP_OFF  731200          // f32 [32][2][64] per-batch BN partials
#define MV_OFF   735296          // alpha[64], beta[64]

// ---- d_out (scr) float offsets; all dead before k_main overwrites ----
#define PART_OFF  0              // [b][chunk32][144][64] DFT+Gram partials
#define SRED2_OFF 9437184        // [b][144][64] chunk-reduced
#define VF_OFF    9732096        // f32 V [b][128][64] (k-major, for k_bn)

static __device__ __forceinline__ u16 f2b(float f) {
  u32 u = __float_as_uint(f);
  return (u16)((u + 0x7FFFu + ((u >> 16) & 1u)) >> 16);   // RNE f32->bf16
}
static __device__ __forceinline__ u16 f2bh(float f) {
  return (u16)((__float_as_uint(f) + 0x8000u) >> 16);     // half-up, 2 ops
}
// pack two floats -> (lo,hi) bf16 pair in one u32 via v_perm
static __device__ __forceinline__ u32 pk2(float lo, float hi) {
  return __builtin_amdgcn_perm(__float_as_uint(hi) + 0x8000u,
                               __float_as_uint(lo) + 0x8000u,
                               0x07060302u);
}

// slot j: j=0 -> sin(m=32); j=1..32 -> cos(m=j); j=33..63 -> sin(m=j-32)
static __device__ __forceinline__ float slot_val(int j, int l) {
  int m = (j == 0) ? 32 : (j <= 32 ? j : j - 32);
  bool is_sin = (j == 0) || (j >= 33);
  int r = (m * l) & (LL - 1);
  float ang = (float)r * (TWOPI / (float)LL);
  return is_sin ? sinf(ang) : cosf(ang);
}

// ---------------------------------------------------------------------------
// Merged table builder.  blocks 0..2047: Tb[l][j]; 2048..4607: Tt[j][l].
__global__ __launch_bounds__(256) void k_tbl(float* __restrict__ ws) {
  int bid = blockIdx.x;
  if (bid < 2048) {
    int idx = bid * 256 + threadIdx.x;        // < 8192*64
    int l = idx >> 6, j = idx & 63;
    ((u16*)ws)[TBLM_OFF * 2 + idx] = f2b(slot_val(j, l));
  } else {
    int bb = bid - 2048;
    int j = bb >> 5;                          // 0..79
    int l = (bb & 31) * 256 + threadIdx.x;
    float v = (j < 64) ? slot_val(j, l) : (j == 64 ? 1.0f : 0.0f);
    ((u16*)ws)[TTD_OFF * 2 + j * LL + l] = f2b(v);
  }
}

// ---------------------------------------------------------------------------
// Phase A: DFT partials (80 rows) + Gram x^Tx partials (64 rows) via MFMA.
// 1024 blocks x 576 (9 waves): w0..4 slot rows (A from table), w5..8 Gram.
// Double-buffered LDS, async-stage split, lane-owns-channel-row staging
// (coalesced loads; 2x ds_write_b128 along l -> bank-floor writes).
__global__ __launch_bounds__(576) void k_dft(const float* __restrict__ x,
                                             const float* __restrict__ ws,
                                             float* __restrict__ scr) {
  __shared__ __align__(16) u16 sX[2][64 * 136];   // [ch][l'] bf16, 272B rows
  int tid = threadIdx.x;
  int b = blockIdx.x >> 5, chunk = blockIdx.x & 31;
  int l0 = chunk * 256;
  int w = tid >> 6, lane = tid & 63;
  const u16* tt = (const u16*)ws + TTD_OFF * 2;

  f32x4 acc[4];
#pragma unroll
  for (int ct = 0; ct < 4; ++ct) acc[ct] = (f32x4){0.f, 0.f, 0.f, 0.f};

  int arow = lane & 15;
  int kb = (lane >> 4) * 8;                       // u16 units
  bool isg = (w >= 5);
  int gi = w - 5;
  bool stg = (tid < 512);
  int sc = tid & 63, lg = (tid >> 6) & 7;         // staging: channel, l-group

  float vx[16];
  // ---- load+write tile 0 ----
  if (stg) {
#pragma unroll
    for (int i = 0; i < 16; ++i)
      vx[i] = x[(b * LL + l0 + lg * 16 + i) * 64 + sc];
    u32 wv[8];
#pragma unroll
    for (int j = 0; j < 8; ++j) wv[j] = pk2(vx[2 * j], vx[2 * j + 1]);
    u32x4* dst = (u32x4*)&sX[0][sc * 136 + lg * 16];
    dst[0] = (u32x4){wv[0], wv[1], wv[2], wv[3]};
    dst[1] = (u32x4){wv[4], wv[5], wv[6], wv[7]};
  }
  __syncthreads();

  // ---- issue loads for tile 1 (hide under MFMA of tile 0) ----
  if (stg) {
#pragma unroll
    for (int i = 0; i < 16; ++i)
      vx[i] = x[(b * LL + l0 + 128 + lg * 16 + i) * 64 + sc];
  }

  // ---- MFMA tile 0 ----
#pragma unroll
  for (int kk = 0; kk < 4; ++kk) {
    short8 a = isg
      ? *reinterpret_cast<const short8*>(&sX[0][(gi * 16 + arow) * 136 + kk * 32 + kb])
      : *reinterpret_cast<const short8*>(tt + (w * 16 + arow) * LL + l0 + kk * 32 + kb);
#pragma unroll
    for (int ct = 0; ct < 4; ++ct) {
      short8 bf = *reinterpret_cast<const short8*>(&sX[0][(ct * 16 + arow) * 136 + kk * 32 + kb]);
      acc[ct] = __builtin_amdgcn_mfma_f32_16x16x32_bf16(a, bf, acc[ct], 0, 0, 0);
    }
  }

  // ---- write tile 1 ----
  if (stg) {
    u32 wv[8];
#pragma unroll
    for (int j = 0; j < 8; ++j) wv[j] = pk2(vx[2 * j], vx[2 * j + 1]);
    u32x4* dst = (u32x4*)&sX[1][sc * 136 + lg * 16];
    dst[0] = (u32x4){wv[0], wv[1], wv[2], wv[3]};
    dst[1] = (u32x4){wv[4], wv[5], wv[6], wv[7]};
  }
  __syncthreads();

  // ---- MFMA tile 1 ----
#pragma unroll
  for (int kk = 0; kk < 4; ++kk) {
    short8 a = isg
      ? *reinterpret_cast<const short8*>(&sX[1][(gi * 16 + arow) * 136 + kk * 32 + kb])
      : *reinterpret_cast<const short8*>(tt + (w * 16 + arow) * LL + l0 + 128 + kk * 32 + kb);
#pragma unroll
    for (int ct = 0; ct < 4; ++ct) {
      short8 bf = *reinterpret_cast<const short8*>(&sX[1][(ct * 16 + arow) * 136 + kk * 32 + kb]);
      acc[ct] = __builtin_amdgcn_mfma_f32_16x16x32_bf16(a, bf, acc[ct], 0, 0, 0);
    }
  }

  int rowbase = isg ? (80 + gi * 16) : (w * 16);
  int rowb = (lane >> 4) * 4;
#pragma unroll
  for (int ct = 0; ct < 4; ++ct) {
    int col = ct * 16 + (lane & 15);
#pragma unroll
    for (int r = 0; r < 4; ++r)
      scr[PART_OFF + ((b * 32 + chunk) * 144 + rowbase + rowb + r) * 64 + col] = acc[ct][r];
  }
}

// ---------------------------------------------------------------------------
// Reduce partials over 32 chunks -> SRED2[b][144][64].  grid (36, 32).
__global__ __launch_bounds__(256) void k_red1(float* __restrict__ scr) {
  int b = blockIdx.y;
  int r = blockIdx.x * 256 + threadIdx.x;     // < 9216
  float a = 0.f;
#pragma unroll 8
  for (int ch = 0; ch < 32; ++ch) a += scr[PART_OFF + (b * 32 + ch) * 9216 + r];
  scr[SRED2_OFF + b * 9216 + r] = a;
}

// ---------------------------------------------------------------------------
// psi = t_emb @ psi_kernel ; t_c = t_emb @ dense_{re,im}.  32 blocks.
__global__ __launch_bounds__(256) void k_small(const float* __restrict__ t_emb,
                                               const float* __restrict__ dre,
                                               const float* __restrict__ dim_,
                                               const float* __restrict__ pk,
                                               float* __restrict__ ws) {
  __shared__ float sT[TE];
  int tid = threadIdx.x, b = blockIdx.x;
  sT[tid] = t_emb[b * TE + tid];
  __syncthreads();
  if (tid < 128) {
    float a = 0.f;
#pragma unroll 8
    for (int j = 0; j < TE; ++j) a = fmaf(sT[j], pk[j * 128 + tid], a);
    ws[PSI_OFF + b * 128 + tid] = a;
  } else if (tid < 128 + 66) {
    int tt = tid - 128;
    int m = (tt < 33) ? tt : tt - 33;
    const float* dd = (tt < 33) ? dre : dim_;
    float a = 0.f;
#pragma unroll 8
    for (int j = 0; j < TE; ++j) a = fmaf(sT[j], dd[j * MM + m], a);
    ws[TC_OFF + b * 66 + tt] = a;
  }
}

// ---------------------------------------------------------------------------
// Spectral contraction, one block per mode m (33 blocks x 256).
__global__ __launch_bounds__(256) void k_spec(const float* __restrict__ swr,
                                              const float* __restrict__ swi,
                                              float* __restrict__ scr,
                                              float* __restrict__ ws) {
  __shared__ float2 sW[64 * 64];   // [i][o] (re,im)
  __shared__ float2 sX[32 * 64];   // [b][i] (re,im)
  __shared__ float sTcb[64];
  int tid = threadIdx.x, m = blockIdx.x;

  for (int idx = tid; idx < 4096; idx += 256)
    sW[idx] = make_float2(swr[m * 4096 + idx], swi[m * 4096 + idx]);
  for (int idx = tid; idx < 2048; idx += 256) {
    int b = idx >> 6, i = idx & 63;
    const float* sr = scr + SRED2_OFF + b * 9216;
    float xr, xi;
    if (m == 0)      { xr = sr[64 * 64 + i] * INVL;  xi = 0.f; }
    else if (m < 32) { xr = sr[m * 64 + i] * INVL;   xi = -sr[(32 + m) * 64 + i] * INVL; }
    else             { xr = sr[32 * 64 + i] * INVL;  xi = -sr[0 * 64 + i] * INVL; }
    sX[idx] = make_float2(xr, xi);
  }
  if (tid < 64) {
    int b = tid & 31, half = tid >> 5;
    sTcb[tid] = ws[TC_OFF + b * 66 + half * 33 + m];
  }
  __syncthreads();

  int w = tid >> 6, lane = tid & 63;
  for (int p = 0; p < 8; ++p) {
    int b = p * 4 + w;
    float a0 = 0.f, a1 = 0.f, a2 = 0.f, a3 = 0.f;
#pragma unroll 16
    for (int i = 0; i < 64; ++i) {
      float2 wv = sW[i * 64 + lane];
      float2 xv = sX[b * 64 + i];
      a0 = fmaf(xv.x, wv.x, a0);
      a1 = fmaf(xv.y, wv.y, a1);
      a2 = fmaf(xv.x, wv.y, a2);
      a3 = fmaf(xv.y, wv.x, a3);
    }
    float ar = a0 - a1, ai = a2 + a3;
    float tcr = sTcb[b], tci = sTcb[32 + b];
    float cr = tcr * ar - tci * ai;
    float ci = tcr * ai + tci * ar;
    if (m == 0) {
      ws[DD2_OFF + b * 64 + lane] = cr;
    } else {
      float crr = 2.f * cr, cii = -2.f * ci;
      int js = (m == 32) ? 0 : 32 + m;
      u16* vtb = (u16*)ws + VTB_OFF * 2 + (b * 64 + lane) * 128;
      vtb[64 + m] = f2b(crr);
      vtb[64 + js] = f2b(cii);
      float* vf = scr + VF_OFF + b * 8192;
      vf[(64 + m) * 64 + lane] = crr;
      vf[(64 + js) * 64 + lane] = cii;
    }
  }
}

// ---------------------------------------------------------------------------
// M2[b][c][o] = sum_j ck[c,j] psi[b,j] tw[o,j] -> V rows 0..63; D1[b][o].
__global__ __launch_bounds__(256) void k_m2(const float* __restrict__ ck,
                                            const float* __restrict__ cbias,
                                            const float* __restrict__ tw,
                                            float* __restrict__ scr,
                                            float* __restrict__ ws) {
  __shared__ float sCkT[64 * 64];   // [j][c]
  __shared__ float sPtw[64 * 64];   // [o][j]
  __shared__ float sPsi[128];
  int tid = threadIdx.x, b = blockIdx.x;

  if (tid < 128) sPsi[tid] = ws[PSI_OFF + b * 128 + tid];
  __syncthreads();
  for (int idx = tid; idx < 4096; idx += 256) {
    int c = idx >> 6, j = idx & 63;
    sCkT[j * 64 + c] = ck[idx];
    sPtw[idx] = sPsi[j] * tw[idx];
  }
  __syncthreads();

  u16* vtb = (u16*)ws + VTB_OFF * 2 + b * 64 * 128;
  float* vf = scr + VF_OFF + b * 8192;
  int lane = tid & 63, w = tid >> 6;
#pragma unroll 4
  for (int it = 0; it < 16; ++it) {
    int o = it * 4 + w;
    float a = 0.f;
#pragma unroll 16
    for (int j = 0; j < 64; ++j)
      a = fmaf(sCkT[j * 64 + lane], sPtw[o * 64 + j], a);
    vtb[o * 128 + lane] = f2b(a);
    vf[lane * 64 + o] = a;
  }
  if (tid < 64) {
    float a = 0.f;
    for (int j = 0; j < 64; ++j) a = fmaf(cbias[j], sPtw[tid * 64 + j], a);
    ws[DD_OFF + b * 64 + tid] = a + sPsi[64 + tid];
  }
}

// ---------------------------------------------------------------------------
// Analytic BN partials per batch (see round-5 derivation).
__global__ __launch_bounds__(256) void k_bn(const float* __restrict__ scr,
                                            float* __restrict__ ws) {
  __shared__ float sVx[64 * 64];
  __shared__ float sGx[64 * 64];
  __shared__ float sS[64 * 64];
  __shared__ float sSum[64];
  __shared__ float sP[4][2][64];
  int tid = threadIdx.x, b = blockIdx.x;
  const float* sr = scr + SRED2_OFF + b * 9216;
  const float* vf = scr + VF_OFF + b * 8192;

  for (int p = tid; p < 4096; p += 256) {
    sVx[p] = vf[p];              // V rows 0..63
    sGx[p] = sr[80 * 64 + p];    // Gram rows
    sS[p]  = sr[p];              // slot rows 0..63
  }
  if (tid < 64) sSum[tid] = sr[64 * 64 + tid];
  __syncthreads();

  int o = tid & 63, part = tid >> 6;
  float m1 = 0.f, q1 = 0.f, cross = 0.f, vt2 = 0.f;
  for (int ii = 0; ii < 16; ++ii) {
    int i = part * 16 + ii;
    float vx = sVx[i * 64 + o];
    m1 = fmaf(sSum[i], vx, m1);
    float w0 = 0.f, w1 = 0.f, c0 = 0.f, c1 = 0.f;
#pragma unroll
    for (int j = 0; j < 64; j += 2) {
      float va = sVx[j * 64 + o], vb = sVx[(j + 1) * 64 + o];
      w0 = fmaf(sGx[i * 64 + j], va, w0);
      w1 = fmaf(sGx[i * 64 + j + 1], vb, w1);
      c0 = fmaf(sS[i * 64 + j], va, c0);
      c1 = fmaf(sS[i * 64 + j + 1], vb, c1);
    }
    q1 = fmaf(vx, w0 + w1, q1);
    float vt = vf[(64 + i) * 64 + o];
    vt2 = fmaf(vt, vt, vt2);
    cross = fmaf(vt, c0 + c1, cross);
  }
  sP[part][0][o] = m1;
  sP[part][1][o] = q1 + 2.f * cross + 4096.f * vt2;   // L/2 = 4096
  __syncthreads();
  if (tid < 64) {
    float m = sP[0][0][tid] + sP[1][0][tid] + sP[2][0][tid] + sP[3][0][tid];
    float q = sP[0][1][tid] + sP[1][1][tid] + sP[2][1][tid] + sP[3][1][tid];
    float D = ws[DD_OFF + b * 64 + tid] + ws[DD2_OFF + b * 64 + tid];
    ws[BNP_OFF + b * 128 + tid]      = m + 8192.f * D;
    ws[BNP_OFF + b * 128 + 64 + tid] = q + 2.f * D * m + 8192.f * D * D;
  }
}

__global__ __launch_bounds__(64) void k_bn2(const float* __restrict__ bns,
                                            const float* __restrict__ bnb,
                                            float* __restrict__ ws) {
  int o = threadIdx.x;
  float sm = 0.f, sq = 0.f;
#pragma unroll
  for (int b = 0; b < 32; ++b) {
    sm += ws[BNP_OFF + b * 128 + o];
    sq += ws[BNP_OFF + b * 128 + 64 + o];
  }
  const float inv_n = 1.f / (32.f * 8192.f);
  float mean = sm * inv_n;
  float var = sq * inv_n - mean * mean;
  float istd = rsqrtf(var + 1e-5f);
  float alpha = istd * bns[o];
  ws[MV_OFF + o] = alpha;
  ws[MV_OFF + 64 + o] = bnb[o] - mean * alpha;
}

// ---------------------------------------------------------------------------
// Phase C: out = relu(alpha*(U@V + D) + beta) via MFMA.  2048 x 256.
__global__ __launch_bounds__(256) void k_main(const float* __restrict__ x,
                                              const float* __restrict__ ws,
                                              float* __restrict__ out) {
  __shared__ __align__(16) u16 sVt[64 * 136];
  __shared__ float sD[64];
  __shared__ float sA[64];
  __shared__ float sB[64];
  int tid = threadIdx.x, w = tid >> 6, lane = tid & 63;
  int b = blockIdx.x >> 6, rg = blockIdx.x & 63;
  const u16* wsu = (const u16*)ws;

  {
    const u32* src = (const u32*)(wsu + VTB_OFF * 2 + b * 64 * 128);
    u32* dst = (u32*)sVt;
    for (int p = tid; p < 4096; p += 256)
      dst[(p >> 6) * 68 + (p & 63)] = src[p];
  }
  if (tid < 64) {
    sD[tid] = ws[DD_OFF + b * 64 + tid] + ws[DD2_OFF + b * 64 + tid];
    sA[tid] = ws[MV_OFF + tid];
    sB[tid] = ws[MV_OFF + 64 + tid];
  }
  __syncthreads();

  int kb = (lane >> 4) * 8;
  short8 bf[4][4];
#pragma unroll
  for (int kk = 0; kk < 4; ++kk)
#pragma unroll
    for (int ct = 0; ct < 4; ++ct)
      bf[kk][ct] = *reinterpret_cast<const short8*>(
          &sVt[(ct * 16 + (lane & 15)) * 136 + kk * 32 + kb]);

  const u16* tb = wsu + TBLM_OFF * 2;
  int rowb = (lane >> 4) * 4;
  int lbase = rg * 128 + w * 32;

#pragma unroll
  for (int rt = 0; rt < 2; ++rt) {
    int l = lbase + rt * 16 + (lane & 15);
    const float* xq = x + (b * LL + l) * 64;
    float4 u0 = *reinterpret_cast<const float4*>(xq + kb);
    float4 u1 = *reinterpret_cast<const float4*>(xq + kb + 4);
    float4 u2 = *reinterpret_cast<const float4*>(xq + 32 + kb);
    float4 u3 = *reinterpret_cast<const float4*>(xq + 32 + kb + 4);
    union { short8 s; u32 wv[4]; } A0, A1;
    A0.wv[0] = pk2(u0.x, u0.y); A0.wv[1] = pk2(u0.z, u0.w);
    A0.wv[2] = pk2(u1.x, u1.y); A0.wv[3] = pk2(u1.z, u1.w);
    A1.wv[0] = pk2(u2.x, u2.y); A1.wv[1] = pk2(u2.z, u2.w);
    A1.wv[2] = pk2(u3.x, u3.y); A1.wv[3] = pk2(u3.z, u3.w);
    short8 a2 = *reinterpret_cast<const short8*>(tb + l * 64 + kb);
    short8 a3 = *reinterpret_cast<const short8*>(tb + l * 64 + 32 + kb);

    f32x4 acc[4];
#pragma unroll
    for (int ct = 0; ct < 4; ++ct) acc[ct] = (f32x4){0.f, 0.f, 0.f, 0.f};
#pragma unroll
    for (int ct = 0; ct < 4; ++ct) {
      acc[ct] = __builtin_amdgcn_mfma_f32_16x16x32_bf16(A0.s, bf[0][ct], acc[ct], 0, 0, 0);
      acc[ct] = __builtin_amdgcn_mfma_f32_16x16x32_bf16(A1.s, bf[1][ct], acc[ct], 0, 0, 0);
      acc[ct] = __builtin_amdgcn_mfma_f32_16x16x32_bf16(a2, bf[2][ct], acc[ct], 0, 0, 0);
      acc[ct] = __builtin_amdgcn_mfma_f32_16x16x32_bf16(a3, bf[3][ct], acc[ct], 0, 0, 0);
    }
#pragma unroll
    for (int ct = 0; ct < 4; ++ct) {
      int o = ct * 16 + (lane & 15);
      float dd = sD[o], al = sA[o], be = sB[o];
#pragma unroll
      for (int r = 0; r < 4; ++r) {
        float v = acc[ct][r] + dd;
        out[(b * LL + lbase + rt * 16 + rowb + r) * 64 + o] =
            fmaxf(fmaf(v, al, be), 0.f);
      }
    }
  }
}

// ---------------------------------------------------------------------------
extern "C" void kernel_launch(void* const* d_in, const int* in_sizes, int n_in,
                              void* d_out, int out_size, void* d_ws, size_t ws_size,
                              hipStream_t stream) {
  const float* x     = (const float*)d_in[0];
  const float* t_emb = (const float*)d_in[1];
  const float* swr   = (const float*)d_in[2];
  const float* swi   = (const float*)d_in[3];
  const float* dre   = (const float*)d_in[4];
  const float* dim_  = (const float*)d_in[5];
  const float* ck    = (const float*)d_in[6];
  const float* cbias = (const float*)d_in[7];
  const float* tw    = (const float*)d_in[8];
  const float* pk    = (const float*)d_in[9];
  const float* bns   = (const float*)d_in[10];
  const float* bnb   = (const float*)d_in[11];
  float* ws  = (float*)d_ws;
  float* out = (float*)d_out;

  k_tbl<<<4608, 256, 0, stream>>>(ws);
  k_dft<<<1024, 576, 0, stream>>>(x, ws, out);          // partials into d_out
  k_red1<<<dim3(36, 32), 256, 0, stream>>>(out);        // -> SRED2 (in d_out)
  k_small<<<32, 256, 0, stream>>>(t_emb, dre, dim_, pk, ws);
  k_spec<<<33, 256, 0, stream>>>(swr, swi, out, ws);
  k_m2<<<32, 256, 0, stream>>>(ck, cbias, tw, out, ws);
  k_bn<<<32, 256, 0, stream>>>(out, ws);
  k_bn2<<<1, 64, 0, stream>>>(bns, bnb, ws);
  k_main<<<2048, 256, 0, stream>>>(x, ws, out);         // overwrites d_out
}

// Round 8
// 101.440 us; speedup vs baseline: 6.3621x; 1.1420x over previous
//
#include <hip/hip_runtime.h>

typedef short short8 __attribute__((ext_vector_type(8)));
typedef float f32x4 __attribute__((ext_vector_type(4)));
typedef unsigned int u32;
typedef u32 u32x4 __attribute__((ext_vector_type(4)));
typedef unsigned short u16;

#define BB 32
#define LL 8192
#define TE 256
#define MM 33
#define INVL (1.0f/8192.0f)
#define TWOPI 6.28318530717958647692f

// ---- ws float offsets ----
#define TBLM_OFF 0               // Tb bf16 [8192][64]
#define TTD_OFF  262144          // Tt bf16 [80][8192]
#define VTB_OFF  589824          // Vtb bf16 [32][64][128] (V^T for k_main)
#define DD_OFF   720896          // f32 [32][64]  (M2-branch bias)
#define DD2_OFF  722944          // f32 [32][64]  (cos0 spectral bias)
#define BNP_OFF  731200          // f32 [32][2][64] per-batch BN partials

// ---- d_out (scr) float offsets; all dead before k_main overwrites ----
#define PART_OFF  0              // [b][chunk32][144][64] DFT+Gram partials
#define SRED2_OFF 9437184        // [b][144][64] chunk-reduced
#define VF_OFF    9732096        // f32 V [b][128][64] (k-major, for k_bn)

static __device__ __forceinline__ u16 f2b(float f) {
  u32 u = __float_as_uint(f);
  return (u16)((u + 0x7FFFu + ((u >> 16) & 1u)) >> 16);   // RNE f32->bf16
}
// pack two floats -> (lo,hi) bf16 pair in one u32 via v_perm (half-up)
static __device__ __forceinline__ u32 pk2(float lo, float hi) {
  return __builtin_amdgcn_perm(__float_as_uint(hi) + 0x8000u,
                               __float_as_uint(lo) + 0x8000u,
                               0x07060302u);
}

// slot j: j=0 -> sin(m=32); j=1..32 -> cos(m=j); j=33..63 -> sin(m=j-32)
static __device__ __forceinline__ float slot_val(int j, int l) {
  int m = (j == 0) ? 32 : (j <= 32 ? j : j - 32);
  bool is_sin = (j == 0) || (j >= 33);
  int r = (m * l) & (LL - 1);
  float ang = (float)r * (TWOPI / (float)LL);
  return is_sin ? sinf(ang) : cosf(ang);
}

// ---------------------------------------------------------------------------
// Merged table builder.  blocks 0..2047: Tb[l][j]; 2048..4607: Tt[j][l].
__global__ __launch_bounds__(256) void k_tbl(float* __restrict__ ws) {
  int bid = blockIdx.x;
  if (bid < 2048) {
    int idx = bid * 256 + threadIdx.x;        // < 8192*64
    int l = idx >> 6, j = idx & 63;
    ((u16*)ws)[TBLM_OFF * 2 + idx] = f2b(slot_val(j, l));
  } else {
    int bb = bid - 2048;
    int j = bb >> 5;                          // 0..79
    int l = (bb & 31) * 256 + threadIdx.x;
    float v = (j < 64) ? slot_val(j, l) : (j == 64 ? 1.0f : 0.0f);
    ((u16*)ws)[TTD_OFF * 2 + j * LL + l] = f2b(v);
  }
}

// ---------------------------------------------------------------------------
// Phase A: DFT partials (80 rows) + Gram x^Tx partials (64 rows) via MFMA.
// 1024 blocks x 576 (9 waves): w0..4 slot rows (A from table), w5..8 Gram.
__global__ __launch_bounds__(576) void k_dft(const float* __restrict__ x,
                                             const float* __restrict__ ws,
                                             float* __restrict__ scr) {
  __shared__ __align__(16) u16 sX[2][64 * 136];   // [ch][l'] bf16, 272B rows
  int tid = threadIdx.x;
  int b = blockIdx.x >> 5, chunk = blockIdx.x & 31;
  int l0 = chunk * 256;
  int w = tid >> 6, lane = tid & 63;
  const u16* tt = (const u16*)ws + TTD_OFF * 2;

  f32x4 acc[4];
#pragma unroll
  for (int ct = 0; ct < 4; ++ct) acc[ct] = (f32x4){0.f, 0.f, 0.f, 0.f};

  int arow = lane & 15;
  int kb = (lane >> 4) * 8;                       // u16 units
  bool isg = (w >= 5);
  int gi = w - 5;
  bool stg = (tid < 512);
  int sc = tid & 63, lg = (tid >> 6) & 7;         // staging: channel, l-group

  float vx[16];
  if (stg) {
#pragma unroll
    for (int i = 0; i < 16; ++i)
      vx[i] = x[(b * LL + l0 + lg * 16 + i) * 64 + sc];
    u32 wv[8];
#pragma unroll
    for (int j = 0; j < 8; ++j) wv[j] = pk2(vx[2 * j], vx[2 * j + 1]);
    u32x4* dst = (u32x4*)&sX[0][sc * 136 + lg * 16];
    dst[0] = (u32x4){wv[0], wv[1], wv[2], wv[3]};
    dst[1] = (u32x4){wv[4], wv[5], wv[6], wv[7]};
  }
  __syncthreads();

  if (stg) {
#pragma unroll
    for (int i = 0; i < 16; ++i)
      vx[i] = x[(b * LL + l0 + 128 + lg * 16 + i) * 64 + sc];
  }

#pragma unroll
  for (int kk = 0; kk < 4; ++kk) {
    short8 a = isg
      ? *reinterpret_cast<const short8*>(&sX[0][(gi * 16 + arow) * 136 + kk * 32 + kb])
      : *reinterpret_cast<const short8*>(tt + (w * 16 + arow) * LL + l0 + kk * 32 + kb);
#pragma unroll
    for (int ct = 0; ct < 4; ++ct) {
      short8 bf = *reinterpret_cast<const short8*>(&sX[0][(ct * 16 + arow) * 136 + kk * 32 + kb]);
      acc[ct] = __builtin_amdgcn_mfma_f32_16x16x32_bf16(a, bf, acc[ct], 0, 0, 0);
    }
  }

  if (stg) {
    u32 wv[8];
#pragma unroll
    for (int j = 0; j < 8; ++j) wv[j] = pk2(vx[2 * j], vx[2 * j + 1]);
    u32x4* dst = (u32x4*)&sX[1][sc * 136 + lg * 16];
    dst[0] = (u32x4){wv[0], wv[1], wv[2], wv[3]};
    dst[1] = (u32x4){wv[4], wv[5], wv[6], wv[7]};
  }
  __syncthreads();

#pragma unroll
  for (int kk = 0; kk < 4; ++kk) {
    short8 a = isg
      ? *reinterpret_cast<const short8*>(&sX[1][(gi * 16 + arow) * 136 + kk * 32 + kb])
      : *reinterpret_cast<const short8*>(tt + (w * 16 + arow) * LL + l0 + 128 + kk * 32 + kb);
#pragma unroll
    for (int ct = 0; ct < 4; ++ct) {
      short8 bf = *reinterpret_cast<const short8*>(&sX[1][(ct * 16 + arow) * 136 + kk * 32 + kb]);
      acc[ct] = __builtin_amdgcn_mfma_f32_16x16x32_bf16(a, bf, acc[ct], 0, 0, 0);
    }
  }

  int rowbase = isg ? (80 + gi * 16) : (w * 16);
  int rowb = (lane >> 4) * 4;
#pragma unroll
  for (int ct = 0; ct < 4; ++ct) {
    int col = ct * 16 + (lane & 15);
#pragma unroll
    for (int r = 0; r < 4; ++r)
      scr[PART_OFF + ((b * 32 + chunk) * 144 + rowbase + rowb + r) * 64 + col] = acc[ct][r];
  }
}

// ---------------------------------------------------------------------------
// Reduce partials over 32 chunks -> SRED2[b][144][64].  grid (36, 32).
__global__ __launch_bounds__(256) void k_red1(float* __restrict__ scr) {
  int b = blockIdx.y;
  int r = blockIdx.x * 256 + threadIdx.x;     // < 9216
  float a = 0.f;
#pragma unroll 8
  for (int ch = 0; ch < 32; ++ch) a += scr[PART_OFF + (b * 32 + ch) * 9216 + r];
  scr[SRED2_OFF + b * 9216 + r] = a;
}

// ---------------------------------------------------------------------------
// Fused V-builder: blocks 0..32 = spectral mode m (with local t_c),
// blocks 33..64 = M2 for batch b (with local psi).  65 blocks x 256.
__global__ __launch_bounds__(256) void k_vb(
    const float* __restrict__ t_emb, const float* __restrict__ dre,
    const float* __restrict__ dim_, const float* __restrict__ pk,
    const float* __restrict__ swr, const float* __restrict__ swi,
    const float* __restrict__ ck, const float* __restrict__ cbias,
    const float* __restrict__ tw, float* __restrict__ scr,
    float* __restrict__ ws) {
  __shared__ float smem[12352];
  int tid = threadIdx.x;

  if (blockIdx.x < 33) {
    // ---------------- spectral path, mode m ----------------
    int m = blockIdx.x;
    float2* sW = (float2*)smem;                  // [4096] (re,im) = 8192 f
    float2* sX = (float2*)(smem + 8192);         // [2048] = 4096 f
    float* sTcb = smem + 8192 + 4096;            // [64]

    // phase 0: t_emb (all 32 batches) into sW area, compute t_c
    for (int idx = tid; idx < 8192; idx += 256) smem[idx] = t_emb[idx];
    __syncthreads();
    if (tid < 64) {
      int b = tid & 31;
      const float* dd = (tid < 32) ? dre : dim_;
      float a = 0.f;
#pragma unroll 8
      for (int j = 0; j < TE; ++j) a = fmaf(smem[b * 256 + j], dd[j * MM + m], a);
      sTcb[tid] = a;
    }
    __syncthreads();

    // phase 1: stage W and X
    for (int idx = tid; idx < 4096; idx += 256)
      sW[idx] = make_float2(swr[m * 4096 + idx], swi[m * 4096 + idx]);
    for (int idx = tid; idx < 2048; idx += 256) {
      int b = idx >> 6, i = idx & 63;
      const float* sr = scr + SRED2_OFF + b * 9216;
      float xr, xi;
      if (m == 0)      { xr = sr[64 * 64 + i] * INVL;  xi = 0.f; }
      else if (m < 32) { xr = sr[m * 64 + i] * INVL;   xi = -sr[(32 + m) * 64 + i] * INVL; }
      else             { xr = sr[32 * 64 + i] * INVL;  xi = -sr[0 * 64 + i] * INVL; }
      sX[idx] = make_float2(xr, xi);
    }
    __syncthreads();

    int w = tid >> 6, lane = tid & 63;
    for (int p = 0; p < 8; ++p) {
      int b = p * 4 + w;
      float a0 = 0.f, a1 = 0.f, a2 = 0.f, a3 = 0.f;
#pragma unroll 16
      for (int i = 0; i < 64; ++i) {
        float2 wv = sW[i * 64 + lane];
        float2 xv = sX[b * 64 + i];
        a0 = fmaf(xv.x, wv.x, a0);
        a1 = fmaf(xv.y, wv.y, a1);
        a2 = fmaf(xv.x, wv.y, a2);
        a3 = fmaf(xv.y, wv.x, a3);
      }
      float ar = a0 - a1, ai = a2 + a3;
      float tcr = sTcb[b], tci = sTcb[32 + b];
      float cr = tcr * ar - tci * ai;
      float ci = tcr * ai + tci * ar;
      if (m == 0) {
        ws[DD2_OFF + b * 64 + lane] = cr;
      } else {
        float crr = 2.f * cr, cii = -2.f * ci;
        int js = (m == 32) ? 0 : 32 + m;
        u16* vtb = (u16*)ws + VTB_OFF * 2 + (b * 64 + lane) * 128;
        vtb[64 + m] = f2b(crr);
        vtb[64 + js] = f2b(cii);
        float* vf = scr + VF_OFF + b * 8192;
        vf[(64 + m) * 64 + lane] = crr;
        vf[(64 + js) * 64 + lane] = cii;
      }
    }
  } else {
    // ---------------- M2 path, batch b ----------------
    int b = blockIdx.x - 33;
    float* sCkT = smem;              // [j][c] 4096
    float* sPtw = smem + 4096;       // [o][j] 4096
    float* sTe  = smem + 8192;       // [256]
    float* sPsi = smem + 8448;       // [128]

    sTe[tid] = t_emb[b * 256 + tid];
    __syncthreads();
    if (tid < 128) {
      float a = 0.f;
#pragma unroll 8
      for (int j = 0; j < TE; ++j) a = fmaf(sTe[j], pk[j * 128 + tid], a);
      sPsi[tid] = a;
    }
    __syncthreads();
    for (int idx = tid; idx < 4096; idx += 256) {
      int c = idx >> 6, j = idx & 63;
      sCkT[j * 64 + c] = ck[idx];
      sPtw[idx] = sPsi[j] * tw[idx];
    }
    __syncthreads();

    u16* vtb = (u16*)ws + VTB_OFF * 2 + b * 64 * 128;
    float* vf = scr + VF_OFF + b * 8192;
    int lane = tid & 63, w = tid >> 6;
#pragma unroll 4
    for (int it = 0; it < 16; ++it) {
      int o = it * 4 + w;
      float a = 0.f;
#pragma unroll 16
      for (int j = 0; j < 64; ++j)
        a = fmaf(sCkT[j * 64 + lane], sPtw[o * 64 + j], a);
      vtb[o * 128 + lane] = f2b(a);
      vf[lane * 64 + o] = a;
    }
    if (tid < 64) {
      float a = 0.f;
      for (int j = 0; j < 64; ++j) a = fmaf(cbias[j], sPtw[tid * 64 + j], a);
      ws[DD_OFF + b * 64 + tid] = a + sPsi[64 + tid];
    }
  }
}

// ---------------------------------------------------------------------------
// Analytic BN partials per batch (round-5 derivation).  32 blocks x 256.
__global__ __launch_bounds__(256) void k_bn(const float* __restrict__ scr,
                                            float* __restrict__ ws) {
  __shared__ float sVx[64 * 64];
  __shared__ float sGx[64 * 64];
  __shared__ float sS[64 * 64];
  __shared__ float sSum[64];
  __shared__ float sP[4][2][64];
  int tid = threadIdx.x, b = blockIdx.x;
  const float* sr = scr + SRED2_OFF + b * 9216;
  const float* vf = scr + VF_OFF + b * 8192;

  for (int p = tid; p < 4096; p += 256) {
    sVx[p] = vf[p];              // V rows 0..63
    sGx[p] = sr[80 * 64 + p];    // Gram rows
    sS[p]  = sr[p];              // slot rows 0..63
  }
  if (tid < 64) sSum[tid] = sr[64 * 64 + tid];
  __syncthreads();

  int o = tid & 63, part = tid >> 6;
  float m1 = 0.f, q1 = 0.f, cross = 0.f, vt2 = 0.f;
  for (int ii = 0; ii < 16; ++ii) {
    int i = part * 16 + ii;
    float vx = sVx[i * 64 + o];
    m1 = fmaf(sSum[i], vx, m1);
    float w0 = 0.f, w1 = 0.f, c0 = 0.f, c1 = 0.f;
#pragma unroll
    for (int j = 0; j < 64; j += 2) {
      float va = sVx[j * 64 + o], vb = sVx[(j + 1) * 64 + o];
      w0 = fmaf(sGx[i * 64 + j], va, w0);
      w1 = fmaf(sGx[i * 64 + j + 1], vb, w1);
      c0 = fmaf(sS[i * 64 + j], va, c0);
      c1 = fmaf(sS[i * 64 + j + 1], vb, c1);
    }
    q1 = fmaf(vx, w0 + w1, q1);
    float vt = vf[(64 + i) * 64 + o];
    vt2 = fmaf(vt, vt, vt2);
    cross = fmaf(vt, c0 + c1, cross);
  }
  sP[part][0][o] = m1;
  sP[part][1][o] = q1 + 2.f * cross + 4096.f * vt2;   // L/2 = 4096
  __syncthreads();
  if (tid < 64) {
    float m = sP[0][0][tid] + sP[1][0][tid] + sP[2][0][tid] + sP[3][0][tid];
    float q = sP[0][1][tid] + sP[1][1][tid] + sP[2][1][tid] + sP[3][1][tid];
    float D = ws[DD_OFF + b * 64 + tid] + ws[DD2_OFF + b * 64 + tid];
    ws[BNP_OFF + b * 128 + tid]      = m + 8192.f * D;
    ws[BNP_OFF + b * 128 + 64 + tid] = q + 2.f * D * m + 8192.f * D * D;
  }
}

// ---------------------------------------------------------------------------
// Phase C: out = relu(alpha*(U@V + D) + beta) via MFMA, with in-block
// alpha/beta finalization from BNP (replaces k_bn2).  2048 x 256.
__global__ __launch_bounds__(256) void k_main(const float* __restrict__ x,
                                              const float* __restrict__ ws,
                                              const float* __restrict__ bns,
                                              const float* __restrict__ bnb,
                                              float* __restrict__ out) {
  __shared__ __align__(16) u16 sVt[64 * 136];
  __shared__ float sD[64];
  __shared__ float sA[64];
  __shared__ float sB[64];
  __shared__ float sPp[4][64];
  __shared__ float sPq[4][64];
  int tid = threadIdx.x, w = tid >> 6, lane = tid & 63;
  int b = blockIdx.x >> 6, rg = blockIdx.x & 63;
  const u16* wsu = (const u16*)ws;

  {
    const u32* src = (const u32*)(wsu + VTB_OFF * 2 + b * 64 * 128);
    u32* dst = (u32*)sVt;
    for (int p = tid; p < 4096; p += 256)
      dst[(p >> 6) * 68 + (p & 63)] = src[p];
  }
  {
    int o = tid & 63, g = tid >> 6;
    float pm = 0.f, pq = 0.f;
#pragma unroll
    for (int r = 0; r < 8; ++r) {
      int bb = g * 8 + r;
      pm += ws[BNP_OFF + bb * 128 + o];
      pq += ws[BNP_OFF + bb * 128 + 64 + o];
    }
    sPp[g][o] = pm;
    sPq[g][o] = pq;
  }
  if (tid < 64) sD[tid] = ws[DD_OFF + b * 64 + tid] + ws[DD2_OFF + b * 64 + tid];
  __syncthreads();
  if (tid < 64) {
    const float inv_n = 1.f / (32.f * 8192.f);
    float mean = (sPp[0][tid] + sPp[1][tid] + sPp[2][tid] + sPp[3][tid]) * inv_n;
    float ex2  = (sPq[0][tid] + sPq[1][tid] + sPq[2][tid] + sPq[3][tid]) * inv_n;
    float var = ex2 - mean * mean;
    float istd = rsqrtf(var + 1e-5f);
    float al = istd * bns[tid];
    sA[tid] = al;
    sB[tid] = bnb[tid] - mean * al;
  }
  __syncthreads();

  int kb = (lane >> 4) * 8;
  short8 bf[4][4];
#pragma unroll
  for (int kk = 0; kk < 4; ++kk)
#pragma unroll
    for (int ct = 0; ct < 4; ++ct)
      bf[kk][ct] = *reinterpret_cast<const short8*>(
          &sVt[(ct * 16 + (lane & 15)) * 136 + kk * 32 + kb]);

  const u16* tb = wsu + TBLM_OFF * 2;
  int rowb = (lane >> 4) * 4;
  int lbase = rg * 128 + w * 32;

#pragma unroll
  for (int rt = 0; rt < 2; ++rt) {
    int l = lbase + rt * 16 + (lane & 15);
    const float* xq = x + (b * LL + l) * 64;
    float4 u0 = *reinterpret_cast<const float4*>(xq + kb);
    float4 u1 = *reinterpret_cast<const float4*>(xq + kb + 4);
    float4 u2 = *reinterpret_cast<const float4*>(xq + 32 + kb);
    float4 u3 = *reinterpret_cast<const float4*>(xq + 32 + kb + 4);
    union { short8 s; u32 wv[4]; } A0, A1;
    A0.wv[0] = pk2(u0.x, u0.y); A0.wv[1] = pk2(u0.z, u0.w);
    A0.wv[2] = pk2(u1.x, u1.y); A0.wv[3] = pk2(u1.z, u1.w);
    A1.wv[0] = pk2(u2.x, u2.y); A1.wv[1] = pk2(u2.z, u2.w);
    A1.wv[2] = pk2(u3.x, u3.y); A1.wv[3] = pk2(u3.z, u3.w);
    short8 a2 = *reinterpret_cast<const short8*>(tb + l * 64 + kb);
    short8 a3 = *reinterpret_cast<const short8*>(tb + l * 64 + 32 + kb);

    f32x4 acc[4];
#pragma unroll
    for (int ct = 0; ct < 4; ++ct) acc[ct] = (f32x4){0.f, 0.f, 0.f, 0.f};
#pragma unroll
    for (int ct = 0; ct < 4; ++ct) {
      acc[ct] = __builtin_amdgcn_mfma_f32_16x16x32_bf16(A0.s, bf[0][ct], acc[ct], 0, 0, 0);
      acc[ct] = __builtin_amdgcn_mfma_f32_16x16x32_bf16(A1.s, bf[1][ct], acc[ct], 0, 0, 0);
      acc[ct] = __builtin_amdgcn_mfma_f32_16x16x32_bf16(a2, bf[2][ct], acc[ct], 0, 0, 0);
      acc[ct] = __builtin_amdgcn_mfma_f32_16x16x32_bf16(a3, bf[3][ct], acc[ct], 0, 0, 0);
    }
#pragma unroll
    for (int ct = 0; ct < 4; ++ct) {
      int o = ct * 16 + (lane & 15);
      float dd = sD[o], al = sA[o], be = sB[o];
#pragma unroll
      for (int r = 0; r < 4; ++r) {
        float v = acc[ct][r] + dd;
        out[(b * LL + lbase + rt * 16 + rowb + r) * 64 + o] =
            fmaxf(fmaf(v, al, be), 0.f);
      }
    }
  }
}

// ---------------------------------------------------------------------------
extern "C" void kernel_launch(void* const* d_in, const int* in_sizes, int n_in,
                              void* d_out, int out_size, void* d_ws, size_t ws_size,
                              hipStream_t stream) {
  const float* x     = (const float*)d_in[0];
  const float* t_emb = (const float*)d_in[1];
  const float* swr   = (const float*)d_in[2];
  const float* swi   = (const float*)d_in[3];
  const float* dre   = (const float*)d_in[4];
  const float* dim_  = (const float*)d_in[5];
  const float* ck    = (const float*)d_in[6];
  const float* cbias = (const float*)d_in[7];
  const float* tw    = (const float*)d_in[8];
  const float* pk    = (const float*)d_in[9];
  const float* bns   = (const float*)d_in[10];
  const float* bnb   = (const float*)d_in[11];
  float* ws  = (float*)d_ws;
  float* out = (float*)d_out;

  k_tbl<<<4608, 256, 0, stream>>>(ws);
  k_dft<<<1024, 576, 0, stream>>>(x, ws, out);          // partials into d_out
  k_red1<<<dim3(36, 32), 256, 0, stream>>>(out);        // -> SRED2 (in d_out)
  k_vb<<<65, 256, 0, stream>>>(t_emb, dre, dim_, pk, swr, swi,
                               ck, cbias, tw, out, ws);
  k_bn<<<32, 256, 0, stream>>>(out, ws);
  k_main<<<2048, 256, 0, stream>>>(x, ws, bns, bnb, out); // overwrites d_out
}